// Round 16
// baseline (198.199 us; speedup 1.0000x reference)
//
#include <hip/hip_runtime.h>
#include <hip/hip_bf16.h>
#include <math.h>

// S4DConv via MFMA: B=8, L=2048, H=512, N=64, CH=1
//   r16: k_kfg re-tiled to 64x128 (256 blocks, full chip); k_kgen merged into
//   k_tabs (5 launches). GEMM cores/epilogues identical to r15.

namespace {
constexpr int cB = 8;
constexpr int cL = 2048;
constexpr int cH = 512;
constexpr int cN = 64;
constexpr int M1 = 4095;
constexpr int M2 = 4096;
constexpr int BH = cB * cH;            // 4096
constexpr int MA = BH + cH;            // 4608

constexpr size_t S0   = 2 * ((size_t)cH * cN * 6);
constexpr size_t S_B1 = S0;                           // [4096][2048] paired
constexpr size_t S_A  = S_B1 + (size_t)4096 * 2048;   // [4608][2048]
constexpr size_t S_T2 = S_A  + (size_t)MA * 2048;     // B2 [2][1024][2048]
constexpr size_t S_U  = S_T2 + (size_t)2048 * 4096;   // [4608][4096]: rows<4096 Ae|Ao; 4096+ KF
}

typedef __attribute__((ext_vector_type(8))) short short8;
typedef __attribute__((ext_vector_type(4))) float f32x4;

static __device__ inline short f2bf(float x) {
    __hip_bfloat16 h = __float2bfloat16(x);
    return *reinterpret_cast<short*>(&h);
}
static __device__ inline float bf2f(short s) {
    return __uint_as_float(((unsigned int)(unsigned short)s) << 16);
}
static __device__ __forceinline__ void load_lds16(const short* g, short* l) {
    __builtin_amdgcn_global_load_lds(
        (const __attribute__((address_space(1))) void*)g,
        (__attribute__((address_space(3))) void*)l, 16, 0, 0);
}
#define WAIT_LGKM0() do { asm volatile("s_waitcnt lgkmcnt(0)" ::: "memory"); \
                          __builtin_amdgcn_sched_barrier(0); } while (0)
#define WAIT_LGKM(n) do { asm volatile("s_waitcnt lgkmcnt(" #n ")" ::: "memory"); \
                          __builtin_amdgcn_sched_barrier(0); } while (0)
#define WAIT_VM(n)   do { asm volatile("s_waitcnt vmcnt(" #n ")" ::: "memory"); \
                          __builtin_amdgcn_sched_barrier(0); } while (0)
#define BAR() __builtin_amdgcn_s_barrier()

// blocks <2048: B1'' rows; <4096: B2 parity rows; else: k-row gen (h=bid-4096)
__global__ __launch_bounds__(256) void k_tabs(
    const float* __restrict__ w_re, const float* __restrict__ w_im,
    const float* __restrict__ C_re, const float* __restrict__ C_im,
    const float* __restrict__ dt, short* __restrict__ Wb)
{
    __shared__ float md[cN * 6];
    int tid = threadIdx.x;
    if (blockIdx.x < 2048) {              // B1'' rows for DFT j
        int j  = blockIdx.x;
        int base = (j < 1024) ? 4 * j : (j == 1024 ? 2 : 4 * (2048 - j) + 2);
        int t0 = tid * 8;
        int p0 = (int)(((long)j * t0) % M1);
        float c, s, cs, ss;
        sincosf((6.283185307179586f / (float)M1) * (float)p0, &s, &c);
        sincosf((6.283185307179586f / (float)M1) * (float)j,  &ss, &cs);
        short8 vc, vs;
#pragma unroll
        for (int i = 0; i < 8; ++i) {
            vc[i] = f2bf(c); vs[i] = f2bf(s);
            float tr = c * cs - s * ss;
            s = c * ss + s * cs;
            c = tr;
        }
        *(short8*)&Wb[S_B1 + (size_t)base       * 2048 + t0] = vc;
        *(short8*)&Wb[S_B1 + (size_t)(base + 1) * 2048 + t0] = vs;
    } else if (blockIdx.x < 4096) {       // B2 parity rows
        int r   = blockIdx.x - 2048;
        int p   = r >> 10, tau = r & 1023;
        int t   = 2 * tau + p;
        int k0  = tid * 8;
        float stepang = (6.283185307179586f / (float)M2) * (float)t;
        float cs, ss; sincosf(stepang, &ss, &cs);
        short8 v;
        if (k0 < 1024) {
            int ph = (k0 * t) & (M2 - 1);
            float c, s; sincosf((6.283185307179586f / (float)M2) * (float)ph, &s, &c);
#pragma unroll
            for (int i = 0; i < 8; ++i) {
                v[i] = f2bf(c);
                float tr = c * cs - s * ss;
                s = c * ss + s * cs;
                c = tr;
            }
        } else {
            int j0 = k0 - 1024;
            int ph = (j0 * t) & (M2 - 1);
            float c, s; sincosf((6.283185307179586f / (float)M2) * (float)ph, &s, &c);
#pragma unroll
            for (int i = 0; i < 8; ++i) {
                int k = k0 + i;
                v[i] = (k == 1024) ? f2bf((tau & 1) ? -1.f : 1.f) : f2bf(s);
                float tr = c * cs - s * ss;
                s = c * ss + s * cs;
                c = tr;
            }
        }
        *(short8*)&Wb[S_T2 + (size_t)r * 2048 + k0] = v;
    } else {                              // k-row gen
        int h = blockIdx.x - 4096;
        if (tid < cN) {
            int idx = h * cN + tid;
            double dtv = dt[h];
            double wr = w_re[idx], wi = w_im[idx];
            double ar = wr * dtv, ai = wi * dtv;
            double er = exp(ar);
            double zs, zc; sincos(ai, &zs, &zc);
            double zr = er * zc, zi = er * zs;
            double nr = zr - 1.0, ni = zi;
            double inv = 1.0 / (wr * wr + wi * wi);
            double gr = (nr * wr + ni * wi) * inv;
            double gi = (ni * wr - nr * wi) * inv;
            double cr = C_re[idx], ci = C_im[idx];
            md[tid*6+0] = (float)(cr * gr - ci * gi);
            md[tid*6+1] = (float)(cr * gi + ci * gr);
            md[tid*6+2] = (float)zr; md[tid*6+3] = (float)zi;
            md[tid*6+4] = (float)ar; md[tid*6+5] = (float)ai;
        }
        __syncthreads();
        int t0 = tid * 8;
        float acc[8] = {0.f, 0.f, 0.f, 0.f, 0.f, 0.f, 0.f, 0.f};
        for (int n = 0; n < cN; ++n) {
            float csr = md[n*6+0], csi = md[n*6+1];
            float zr  = md[n*6+2], zi  = md[n*6+3];
            float ar  = md[n*6+4], ai  = md[n*6+5];
            float mag = expf(ar * (float)t0);
            double ph = fmod((double)ai * (double)t0, 6.283185307179586);
            float s, c; sincosf((float)ph, &s, &c);
            float pr = mag * c, pi = mag * s;
#pragma unroll
            for (int i = 0; i < 8; ++i) {
                acc[i] += csr * pr - csi * pi;
                float tr = pr * zr - pi * zi;
                pi = pr * zi + pi * zr;
                pr = tr;
            }
        }
        short8 v;
#pragma unroll
        for (int i = 0; i < 8; ++i) v[i] = f2bf(2.f * acc[i]);
        *reinterpret_cast<short8*>(&Wb[S_A + (size_t)(BH + h) * 2048 + t0]) = v;
    }
}

__global__ __launch_bounds__(256) void k_trans(const float* __restrict__ u,
                                               short* __restrict__ Wb)
{
    __shared__ float tile[64][65];
    int t0 = blockIdx.x * 64;
    int h0 = blockIdx.y * 64;
    int b  = blockIdx.z;
    int cx = threadIdx.x & 63, r0 = threadIdx.x >> 6;
#pragma unroll
    for (int i = 0; i < 16; ++i) {
        int row = r0 + i * 4;
        tile[row][cx] = u[((size_t)b * cL + t0 + row) * cH + h0 + cx];
    }
    __syncthreads();
    short* A = Wb + S_A;
#pragma unroll
    for (int i = 0; i < 16; ++i) {
        int hrow = r0 + i * 4;
        A[(size_t)(b * cH + h0 + hrow) * 2048 + t0 + cx] = f2bf(tile[cx][hrow]);
    }
}

#define MFMA16(AR, BR, ACC) \
    _Pragma("unroll") for (int kk = 0; kk < 2; ++kk) \
    _Pragma("unroll") for (int ni = 0; ni < 2; ++ni) \
    _Pragma("unroll") for (int mi = 0; mi < 4; ++mi) \
        ACC[mi][ni] = __builtin_amdgcn_mfma_f32_16x16x32_bf16(AR[mi][kk], BR[ni][kk], ACC[mi][ni], 0, 0, 0);

// ------- 256x256 core with fragment read-ahead (proven r14/r15) -------------
__device__ __forceinline__ void gemm8p_core(
    const short* __restrict__ Ag, int lda,
    const short* __restrict__ Bg, int ldb,
    int m0, int n0, int nt, short* lds, f32x4 (&acc)[4][4][2])
{
    const int tid  = threadIdx.x;
    const int wave = tid >> 6, lane = tid & 63;
    const int wm = wave >> 2, wn = wave & 3;
    const int lm = lane & 15, lk = lane >> 4;
    const int srow8 = lane >> 3;
    const int scol  = (lane & 7) * 8;

    auto stage = [&](const short* G, int ldg, int row0, int half, int kt, int sb) {
        short* l0 = lds + sb + (size_t)((kt & 1) * 2 + half) * 8192;
#pragma unroll
        for (int q = 0; q < 2; ++q) {
            int chunk = wave * 2 + q;
            int r = chunk * 8 + srow8;
            int c = scol ^ ((r & 7) << 3);
            load_lds16(G + (size_t)(row0 + half * 128 + r) * ldg + kt * 64 + c,
                       l0 + chunk * 512);
        }
    };
    auto rdA = [&](int qa, int kt, int mi, int kk) -> short8 {
        int rl = wm * 64 + mi * 16 + lm;
        int c  = (kk * 32 + lk * 8) ^ ((rl & 7) << 3);
        return *(const short8*)(lds + (size_t)((kt & 1) * 2 + qa) * 8192 + rl * 64 + c);
    };
    auto rdB = [&](int qb, int kt, int ni, int kk) -> short8 {
        int rl = wn * 32 + ni * 16 + lm;
        int c  = (kk * 32 + lk * 8) ^ ((rl & 7) << 3);
        return *(const short8*)(lds + 32768 + (size_t)((kt & 1) * 2 + qb) * 8192 + rl * 64 + c);
    };

    stage(Ag, lda, m0, 0, 0, 0);
    stage(Bg, ldb, n0, 0, 0, 32768);
    stage(Bg, ldb, n0, 1, 0, 32768);
    stage(Ag, lda, m0, 1, 0, 0);
    stage(Ag, lda, m0, 0, 1, 0);
    stage(Bg, ldb, n0, 0, 1, 32768);
    stage(Bg, ldb, n0, 1, 1, 32768);
    stage(Ag, lda, m0, 1, 1, 0);
    WAIT_VM(12);
    BAR();

    short8 a0[4][2], a1[4][2], b0[2][2], b1[2][2], b0n[2][2];
#pragma unroll
    for (int mi = 0; mi < 4; ++mi) { a0[mi][0] = rdA(0, 0, mi, 0); a0[mi][1] = rdA(0, 0, mi, 1); }
#pragma unroll
    for (int ni = 0; ni < 2; ++ni) { b0[ni][0] = rdB(0, 0, ni, 0); b0[ni][1] = rdB(0, 0, ni, 1); }
    WAIT_VM(10);
    BAR();

    for (int t = 0; t < nt; ++t) {
        const bool st = (t + 2 < nt);
        const bool rd = (t + 1 < nt);
        // ---- P0 ----
#pragma unroll
        for (int ni = 0; ni < 2; ++ni) { b1[ni][0] = rdB(1, t, ni, 0); b1[ni][1] = rdB(1, t, ni, 1); }
        BAR();
        WAIT_LGKM(4);
        __builtin_amdgcn_s_setprio(1);
        MFMA16(a0, b0, acc[0]);
        __builtin_amdgcn_s_setprio(0);
        if (rd) { WAIT_VM(8); } else { WAIT_VM(0); }
        BAR();
        // ---- P1 ----
#pragma unroll
        for (int mi = 0; mi < 4; ++mi) { a1[mi][0] = rdA(1, t, mi, 0); a1[mi][1] = rdA(1, t, mi, 1); }
        if (st) { stage(Ag, lda, m0, 0, t + 2, 0); stage(Bg, ldb, n0, 0, t + 2, 32768); }
        BAR();
        WAIT_LGKM(8);
        __builtin_amdgcn_s_setprio(1);
        MFMA16(a0, b1, acc[1]);
        __builtin_amdgcn_s_setprio(0);
        BAR();
        // ---- P2 ----
        if (st) stage(Bg, ldb, n0, 1, t + 2, 32768);
        BAR();
        WAIT_LGKM0();
        __builtin_amdgcn_s_setprio(1);
        MFMA16(a1, b1, acc[3]);
        __builtin_amdgcn_s_setprio(0);
        if (st) { WAIT_VM(10); } else { WAIT_VM(0); }
        BAR();
        // ---- P3 ----
        if (rd) {
#pragma unroll
            for (int mi = 0; mi < 4; ++mi) { a0[mi][0] = rdA(0, t + 1, mi, 0); a0[mi][1] = rdA(0, t + 1, mi, 1); }
#pragma unroll
            for (int ni = 0; ni < 2; ++ni) { b0n[ni][0] = rdB(0, t + 1, ni, 0); b0n[ni][1] = rdB(0, t + 1, ni, 1); }
        }
        if (st) stage(Ag, lda, m0, 1, t + 2, 0);
        BAR();
        __builtin_amdgcn_s_setprio(1);
        MFMA16(a1, b0, acc[2]);
        __builtin_amdgcn_s_setprio(0);
        if (rd) {
#pragma unroll
            for (int ni = 0; ni < 2; ++ni) { b0[ni][0] = b0n[ni][0]; b0[ni][1] = b0n[ni][1]; }
            WAIT_VM(10);
        } else { WAIT_VM(0); }
        BAR();
    }
}

// forward: acc = A_u x B1''^T; epilogue: mix (x KF) + parity fold -> Ae|Ao
__global__ __launch_bounds__(512, 2) void k_fwd8(short* __restrict__ Wb)
{
    __shared__ short lds_s[65536];
    int xcd = blockIdx.x & 7, idx = blockIdx.x >> 3;
    const int m0 = (((xcd >> 1) << 2) + (idx >> 3)) * 256;
    const int n0 = (((xcd & 1) << 3) + (idx & 7)) * 256;
    const int tid = threadIdx.x;
    const int wave = tid >> 6, lane = tid & 63;
    const int wm = wave >> 2, wn = wave & 3;
    const int lm = lane & 15, lk = lane >> 4;

    f32x4 acc[4][4][2] = {};
    gemm8p_core(Wb + S_A, 2048, Wb + S_B1, 2048, m0, n0, 32, lds_s, acc);

    short* Uw = Wb + S_U;
    const short* KF = Wb + S_U;
    short (*M)[136] = (short(*)[136])lds_s;
    for (int q = 0; q < 4; ++q) {
        __syncthreads();
#pragma unroll
        for (int mi = 0; mi < 4; ++mi)
#pragma unroll
        for (int ni = 0; ni < 2; ++ni)
#pragma unroll
        for (int r = 0; r < 4; ++r)
            M[wm * 64 + mi * 16 + lk * 4 + r][wn * 32 + ni * 16 + lm] =
                f2bf(acc[q][mi][ni][r]);
        __syncthreads();
        const int pq0 = (n0 >> 2) + (q & 1) * 32;
        int rl = tid >> 2;
        int cp = (tid & 3) * 8;
        int rowg = m0 + (q >> 1) * 128 + rl;
        int h = rowg & (cH - 1);
        int colg = n0 + (q & 1) * 128 + cp * 4;
        short8 kf4[4], m4[4];
#pragma unroll
        for (int w = 0; w < 4; ++w) {
            kf4[w] = *(const short8*)&KF[(size_t)(4096 + h) * 4096 + colg + w * 8];
            m4[w]  = *(const short8*)&M[rl][cp * 4 + w * 8];
        }
        short8 vce, vse, vco, vso;
#pragma unroll
        for (int i = 0; i < 8; ++i) {
            int w = i >> 1, o = (i & 1) * 4;
            float C  = bf2f(m4[w][o]),   S  = bf2f(m4[w][o+1]);
            float C2 = bf2f(m4[w][o+2]), S2 = bf2f(m4[w][o+3]);
            float Ck  = bf2f(kf4[w][o]),   Sk  = bf2f(kf4[w][o+1]);
            float Ck2 = bf2f(kf4[w][o+2]), Sk2 = bf2f(kf4[w][o+3]);
            int pp = pq0 + cp + i;
            float scp = (pp == 0 ? 1.0f : 2.0f) * (1.0f / (float)M2);
            float scq = 2.0f / (float)M2;
            float yrp = scp * (Ck * C - Sk * S);
            float yip = scp * (Ck * S + Sk * C);
            float yrq = scq * (Ck2 * C2 - Sk2 * S2);
            float yiq = scq * (Ck2 * S2 + Sk2 * C2);
            float ce, co, se, so;
            if (pp == 0) { ce = yrp; co = yrp; se = yrq; so = yiq; }
            else { ce = yrp + yrq; co = yrp - yrq; se = yip - yiq; so = yip + yiq; }
            vce[i] = f2bf(ce); vco[i] = f2bf(co);
            vse[i] = f2bf(se); vso[i] = f2bf(so);
        }
        size_t base = (size_t)rowg * 4096;
        int kx = pq0 + cp;
        *(short8*)&Uw[base + kx]        = vce;
        *(short8*)&Uw[base + 1024 + kx] = vse;
        *(short8*)&Uw[base + 2048 + kx] = vco;
        *(short8*)&Uw[base + 3072 + kx] = vso;
    }
}

// KF rows: U[4096+h] = A_k x B1''^T ; 64x128 tiles, grid (32,8) = 256 blocks
__global__ __launch_bounds__(256, 2) void k_kfg(short* __restrict__ Wb)
{
    __shared__ __align__(16) short As[64][32];
    __shared__ __align__(16) short Bs[128][32];
    const short* A = Wb + S_A;
    const short* B = Wb + S_B1;
    short* U = Wb + S_U;
    const int tid = threadIdx.x;
    const int m0 = 4096 + blockIdx.y * 64, n0 = blockIdx.x * 128;
    const int wave = tid >> 6, lane = tid & 63;
    const int wr = wave >> 1, wc = wave & 1;
    const int lm = lane & 15, lk = lane >> 4;
    const int srowA = tid >> 2,  scolA = (tid & 3) * 8;
    const int srowB = lane >> 2, scolB = (lane & 3) * 8;

    f32x4 acc[2][4] = {};
    for (int k0 = 0; k0 < 2048; k0 += 32) {
        __syncthreads();
        // A: 64x32 = 4KB, 1 load/thread (linear LDS dest)
        load_lds16(&A[(size_t)(m0 + srowA) * 2048 + k0 + scolA],
                   &As[0][0] + wave * 512);
        // B: 128x32 = 8KB, 2 loads/thread
#pragma unroll
        for (int q = 0; q < 2; ++q) {
            int chunk = wave * 2 + q;
            load_lds16(&B[(size_t)(n0 + chunk * 16 + srowB) * 2048 + k0 + scolB],
                       &Bs[chunk * 16][0]);
        }
        __syncthreads();
        short8 a[2];
#pragma unroll
        for (int mi = 0; mi < 2; ++mi)
            a[mi] = *(const short8*)&As[wr*32 + mi*16 + lm][lk*8];
#pragma unroll
        for (int ni = 0; ni < 4; ++ni) {
            short8 b = *(const short8*)&Bs[wc*64 + ni*16 + lm][lk*8];
#pragma unroll
            for (int mi = 0; mi < 2; ++mi)
                acc[mi][ni] = __builtin_amdgcn_mfma_f32_16x16x32_bf16(a[mi], b, acc[mi][ni], 0, 0, 0);
        }
    }
#pragma unroll
    for (int mi = 0; mi < 2; ++mi)
#pragma unroll
    for (int ni = 0; ni < 4; ++ni)
#pragma unroll
    for (int r = 0; r < 4; ++r) {
        int row = m0 + wr*32 + mi*16 + lk*4 + r;
        int col = n0 + wc*64 + ni*16 + lm;
        U[(size_t)row * 4096 + col] = f2bf(acc[mi][ni][r]);
    }
}

// inverse: per parity p, y[2tau+p] = A(e/o) x B2_p^T, K=2048, BM=256 x BN=128
__global__ __launch_bounds__(512, 1) void k_invB(const float* __restrict__ u,
                                                 const float* __restrict__ Dp,
                                                 short* __restrict__ Wb,
                                                 float* __restrict__ out)
{
    __shared__ short lds_s[57344];   // 112 KB
    int xcd = blockIdx.x & 7, idx = blockIdx.x >> 3;
    const int m0 = ((((xcd >> 1) << 2) + (idx >> 3))) * 256;   // bh
    const int nj = ((xcd & 1) << 3) + (idx & 7);               // 0..15
    const int p  = nj >> 3;
    const int n0 = (nj & 7) * 128;                             // tau0
    const int tid = threadIdx.x;
    const int wave = tid >> 6, lane = tid & 63;
    const int wm = wave >> 2, wn = wave & 3;
    const int lm = lane & 15, lk = lane >> 4;
    const int srow8 = lane >> 3;
    const int scol  = (lane & 7) * 8;
    constexpr int nt = 32;
    short* lds = lds_s;
    const short* Ag = Wb + S_U + (size_t)p * 2048;
    const short* Bg = Wb + S_T2 + (size_t)p * 1024 * 2048;

    auto stageA = [&](int half, int kt) {
        short* l0 = lds + (size_t)((kt & 1) * 2 + half) * 8192;
#pragma unroll
        for (int q = 0; q < 2; ++q) {
            int chunk = wave * 2 + q;
            int r = chunk * 8 + srow8;
            int c = scol ^ ((r & 7) << 3);
            load_lds16(Ag + (size_t)(m0 + half * 128 + r) * 4096 + kt * 64 + c,
                       l0 + chunk * 512);
        }
    };
    auto stageB = [&](int kt, int slot) {
        short* l0 = lds + 32768 + (size_t)slot * 8192;
#pragma unroll
        for (int q = 0; q < 2; ++q) {
            int chunk = wave * 2 + q;
            int r = chunk * 8 + srow8;
            int c = scol ^ ((r & 7) << 3);
            load_lds16(Bg + (size_t)(n0 + r) * 2048 + kt * 64 + c,
                       l0 + chunk * 512);
        }
    };
    auto rdA = [&](int half, int kt, int mi, int kk) -> short8 {
        int rl = wm * 64 + mi * 16 + lm;
        int c  = (kk * 32 + lk * 8) ^ ((rl & 7) << 3);
        return *(const short8*)(lds + (size_t)((kt & 1) * 2 + half) * 8192 + rl * 64 + c);
    };
    auto rdB = [&](int slot, int ni, int kk) -> short8 {
        int rl = wn * 32 + ni * 16 + lm;
        int c  = (kk * 32 + lk * 8) ^ ((rl & 7) << 3);
        return *(const short8*)(lds + 32768 + (size_t)slot * 8192 + rl * 64 + c);
    };

    f32x4 acc[2][4][2] = {};

    stageA(0, 0);
    stageB(0, 0);
    stageA(1, 0);
    stageA(0, 1);
    stageB(1, 1);
    stageB(2, 2);
    WAIT_VM(8);
    BAR();
    short8 a0[4][2], a1[4][2], b[2][2], bn[2][2];
#pragma unroll
    for (int mi = 0; mi < 4; ++mi) { a0[mi][0] = rdA(0, 0, mi, 0); a0[mi][1] = rdA(0, 0, mi, 1); }
#pragma unroll
    for (int ni = 0; ni < 2; ++ni) { b[ni][0] = rdB(0, ni, 0); b[ni][1] = rdB(0, ni, 1); }
    WAIT_VM(4);
    BAR();

    int bs = 0;
    for (int t = 0; t < nt; ++t) {
        const bool r1 = (t + 1 < nt);
        const bool s2 = (t + 2 < nt);
        const bool s3 = (t + 3 < nt);
        const bool tail = (t >= nt - 3);
        const int bs2 = (bs == 2) ? 0 : bs + 1;
        // ---- P0 ----
#pragma unroll
        for (int mi = 0; mi < 4; ++mi) { a1[mi][0] = rdA(1, t, mi, 0); a1[mi][1] = rdA(1, t, mi, 1); }
        if (r1) stageA(1, t + 1);
        BAR();
        WAIT_LGKM(8);
        __builtin_amdgcn_s_setprio(1);
        MFMA16(a0, b, acc[0]);
        __builtin_amdgcn_s_setprio(0);
        if (tail) { WAIT_VM(0); } else { WAIT_VM(4); }
        BAR();
        // ---- P1 ----
        if (r1) {
#pragma unroll
            for (int mi = 0; mi < 4; ++mi) { a0[mi][0] = rdA(0, t + 1, mi, 0); a0[mi][1] = rdA(0, t + 1, mi, 1); }
#pragma unroll
            for (int ni = 0; ni < 2; ++ni) { bn[ni][0] = rdB(bs2, ni, 0); bn[ni][1] = rdB(bs2, ni, 1); }
        }
        if (s2) stageA(0, t + 2);
        if (s3) stageB(t + 3, bs);
        BAR();
        if (r1) { WAIT_LGKM(12); } else { WAIT_LGKM0(); }
        __builtin_amdgcn_s_setprio(1);
        MFMA16(a1, b, acc[1]);
        __builtin_amdgcn_s_setprio(0);
        if (r1) {
#pragma unroll
            for (int ni = 0; ni < 2; ++ni) { b[ni][0] = bn[ni][0]; b[ni][1] = bn[ni][1]; }
        }
        if (tail) { WAIT_VM(0); } else { WAIT_VM(4); }
        BAR();
        bs = bs2;
    }

    const int b_  = m0 >> 9;
    const int h00 = m0 & 511;
    float (*T)[132] = (float(*)[132])lds_s;
#pragma unroll
    for (int q = 0; q < 2; ++q) {
        __syncthreads();
#pragma unroll
        for (int mi = 0; mi < 4; ++mi)
#pragma unroll
        for (int ni = 0; ni < 2; ++ni) {
            int tl = wn * 32 + ni * 16 + lm;
            int hl = wm * 64 + mi * 16 + lk * 4;
            *(float4*)&T[tl][hl] = *(float4*)&acc[q][mi][ni];
        }
        __syncthreads();
        int hg = h00 + q * 128 + (tid & 31) * 4;
        float4 dv = *(const float4*)&Dp[hg];
#pragma unroll
        for (int it = 0; it < 8; ++it) {
            int tl = (tid >> 5) + it * 16;
            int tg = 2 * (n0 + tl) + p;
            size_t gidx = ((size_t)b_ * cL + tg) * cH + hg;
            float4 uv = *(const float4*)&u[gidx];
            float4 yv = *(float4*)&T[tl][(tid & 31) * 4];
            yv.x += dv.x * uv.x;
            yv.y += dv.y * uv.y;
            yv.z += dv.z * uv.z;
            yv.w += dv.w * uv.w;
            *(float4*)&out[gidx] = yv;
        }
    }
}

extern "C" void kernel_launch(void* const* d_in, const int* in_sizes, int n_in,
                              void* d_out, int out_size, void* d_ws, size_t ws_size,
                              hipStream_t stream) {
    const float* u    = (const float*)d_in[0];
    const float* w_re = (const float*)d_in[1];
    const float* w_im = (const float*)d_in[2];
    const float* C_re = (const float*)d_in[3];
    const float* C_im = (const float*)d_in[4];
    const float* Dp   = (const float*)d_in[5];
    const float* dt   = (const float*)d_in[6];
    float* out = (float*)d_out;
    short* Wb  = (short*)d_ws;

    hipLaunchKernelGGL(k_tabs,  dim3(4096 + cH), dim3(256), 0, stream,
                       w_re, w_im, C_re, C_im, dt, Wb);
    hipLaunchKernelGGL(k_trans, dim3(cL / 64, cH / 64, cB), dim3(256), 0, stream, u, Wb);
    hipLaunchKernelGGL(k_kfg,   dim3(32, 8), dim3(256), 0, stream, Wb);
    hipLaunchKernelGGL(k_fwd8,  dim3(256), dim3(512), 0, stream, Wb);
    hipLaunchKernelGGL(k_invB,  dim3(256), dim3(512), 0, stream, u, Dp, Wb, out);
}

// Round 17
// 191.375 us; speedup vs baseline: 1.0357x; 1.0357x over previous
//
#include <hip/hip_runtime.h>
#include <hip/hip_bf16.h>
#include <math.h>

// S4DConv via MFMA: B=8, L=2048, H=512, N=64, CH=1
//   r17 = r15 (best measured) + k_kfg retiled 64x128 (256 blocks, full chip).
//   GEMM cores/epilogues byte-identical to r15.

namespace {
constexpr int cB = 8;
constexpr int cL = 2048;
constexpr int cH = 512;
constexpr int cN = 64;
constexpr int M1 = 4095;
constexpr int M2 = 4096;
constexpr int BH = cB * cH;            // 4096
constexpr int MA = BH + cH;            // 4608

constexpr size_t S0   = 2 * ((size_t)cH * cN * 6);
constexpr size_t S_B1 = S0;                           // [4096][2048] paired
constexpr size_t S_A  = S_B1 + (size_t)4096 * 2048;   // [4608][2048]
constexpr size_t S_T2 = S_A  + (size_t)MA * 2048;     // B2 [2][1024][2048]
constexpr size_t S_U  = S_T2 + (size_t)2048 * 4096;   // [4608][4096]: rows<4096 Ae|Ao; 4096+ KF
}

typedef __attribute__((ext_vector_type(8))) short short8;
typedef __attribute__((ext_vector_type(4))) float f32x4;

static __device__ inline short f2bf(float x) {
    __hip_bfloat16 h = __float2bfloat16(x);
    return *reinterpret_cast<short*>(&h);
}
static __device__ inline float bf2f(short s) {
    return __uint_as_float(((unsigned int)(unsigned short)s) << 16);
}
static __device__ __forceinline__ void load_lds16(const short* g, short* l) {
    __builtin_amdgcn_global_load_lds(
        (const __attribute__((address_space(1))) void*)g,
        (__attribute__((address_space(3))) void*)l, 16, 0, 0);
}
#define WAIT_LGKM0() do { asm volatile("s_waitcnt lgkmcnt(0)" ::: "memory"); \
                          __builtin_amdgcn_sched_barrier(0); } while (0)
#define WAIT_LGKM(n) do { asm volatile("s_waitcnt lgkmcnt(" #n ")" ::: "memory"); \
                          __builtin_amdgcn_sched_barrier(0); } while (0)
#define WAIT_VM(n)   do { asm volatile("s_waitcnt vmcnt(" #n ")" ::: "memory"); \
                          __builtin_amdgcn_sched_barrier(0); } while (0)
#define BAR() __builtin_amdgcn_s_barrier()

__global__ __launch_bounds__(256) void k_tabs(short* __restrict__ Wb)
{
    int tid = threadIdx.x;
    if (blockIdx.x < 2048) {              // B1'' rows for DFT j
        int j  = blockIdx.x;
        int base = (j < 1024) ? 4 * j : (j == 1024 ? 2 : 4 * (2048 - j) + 2);
        int t0 = tid * 8;
        int p0 = (int)(((long)j * t0) % M1);
        float c, s, cs, ss;
        sincosf((6.283185307179586f / (float)M1) * (float)p0, &s, &c);
        sincosf((6.283185307179586f / (float)M1) * (float)j,  &ss, &cs);
        short8 vc, vs;
#pragma unroll
        for (int i = 0; i < 8; ++i) {
            vc[i] = f2bf(c); vs[i] = f2bf(s);
            float tr = c * cs - s * ss;
            s = c * ss + s * cs;
            c = tr;
        }
        *(short8*)&Wb[S_B1 + (size_t)base       * 2048 + t0] = vc;
        *(short8*)&Wb[S_B1 + (size_t)(base + 1) * 2048 + t0] = vs;
    } else {                              // B2 parity rows
        int r   = blockIdx.x - 2048;
        int p   = r >> 10, tau = r & 1023;
        int t   = 2 * tau + p;
        int k0  = tid * 8;
        float stepang = (6.283185307179586f / (float)M2) * (float)t;
        float cs, ss; sincosf(stepang, &ss, &cs);
        short8 v;
        if (k0 < 1024) {
            int ph = (k0 * t) & (M2 - 1);
            float c, s; sincosf((6.283185307179586f / (float)M2) * (float)ph, &s, &c);
#pragma unroll
            for (int i = 0; i < 8; ++i) {
                v[i] = f2bf(c);
                float tr = c * cs - s * ss;
                s = c * ss + s * cs;
                c = tr;
            }
        } else {
            int j0 = k0 - 1024;
            int ph = (j0 * t) & (M2 - 1);
            float c, s; sincosf((6.283185307179586f / (float)M2) * (float)ph, &s, &c);
#pragma unroll
            for (int i = 0; i < 8; ++i) {
                int k = k0 + i;
                v[i] = (k == 1024) ? f2bf((tau & 1) ? -1.f : 1.f) : f2bf(s);
                float tr = c * cs - s * ss;
                s = c * ss + s * cs;
                c = tr;
            }
        }
        *(short8*)&Wb[S_T2 + (size_t)r * 2048 + k0] = v;
    }
}

__global__ __launch_bounds__(256) void k_trans(const float* __restrict__ u,
                                               short* __restrict__ Wb)
{
    __shared__ float tile[64][65];
    int t0 = blockIdx.x * 64;
    int h0 = blockIdx.y * 64;
    int b  = blockIdx.z;
    int cx = threadIdx.x & 63, r0 = threadIdx.x >> 6;
#pragma unroll
    for (int i = 0; i < 16; ++i) {
        int row = r0 + i * 4;
        tile[row][cx] = u[((size_t)b * cL + t0 + row) * cH + h0 + cx];
    }
    __syncthreads();
    short* A = Wb + S_A;
#pragma unroll
    for (int i = 0; i < 16; ++i) {
        int hrow = r0 + i * 4;
        A[(size_t)(b * cH + h0 + hrow) * 2048 + t0 + cx] = f2bf(tile[cx][hrow]);
    }
}

__global__ __launch_bounds__(256) void k_kgen(
    const float* __restrict__ w_re, const float* __restrict__ w_im,
    const float* __restrict__ C_re, const float* __restrict__ C_im,
    const float* __restrict__ dt, short* __restrict__ Wb)
{
    __shared__ float md[cN * 6];
    int h = blockIdx.x, tid = threadIdx.x;
    if (tid < cN) {
        int idx = h * cN + tid;
        double dtv = dt[h];
        double wr = w_re[idx], wi = w_im[idx];
        double ar = wr * dtv, ai = wi * dtv;
        double er = exp(ar);
        double zs, zc; sincos(ai, &zs, &zc);
        double zr = er * zc, zi = er * zs;
        double nr = zr - 1.0, ni = zi;
        double inv = 1.0 / (wr * wr + wi * wi);
        double gr = (nr * wr + ni * wi) * inv;
        double gi = (ni * wr - nr * wi) * inv;
        double cr = C_re[idx], ci = C_im[idx];
        md[tid*6+0] = (float)(cr * gr - ci * gi);
        md[tid*6+1] = (float)(cr * gi + ci * gr);
        md[tid*6+2] = (float)zr; md[tid*6+3] = (float)zi;
        md[tid*6+4] = (float)ar; md[tid*6+5] = (float)ai;
    }
    __syncthreads();
    int t0 = tid * 8;
    float acc[8] = {0.f, 0.f, 0.f, 0.f, 0.f, 0.f, 0.f, 0.f};
    for (int n = 0; n < cN; ++n) {
        float csr = md[n*6+0], csi = md[n*6+1];
        float zr  = md[n*6+2], zi  = md[n*6+3];
        float ar  = md[n*6+4], ai  = md[n*6+5];
        float mag = expf(ar * (float)t0);
        double ph = fmod((double)ai * (double)t0, 6.283185307179586);
        float s, c; sincosf((float)ph, &s, &c);
        float pr = mag * c, pi = mag * s;
#pragma unroll
        for (int i = 0; i < 8; ++i) {
            acc[i] += csr * pr - csi * pi;
            float tr = pr * zr - pi * zi;
            pi = pr * zi + pi * zr;
            pr = tr;
        }
    }
    short8 v;
#pragma unroll
    for (int i = 0; i < 8; ++i) v[i] = f2bf(2.f * acc[i]);
    *reinterpret_cast<short8*>(&Wb[S_A + (size_t)(BH + h) * 2048 + t0]) = v;
}

#define MFMA16(AR, BR, ACC) \
    _Pragma("unroll") for (int kk = 0; kk < 2; ++kk) \
    _Pragma("unroll") for (int ni = 0; ni < 2; ++ni) \
    _Pragma("unroll") for (int mi = 0; mi < 4; ++mi) \
        ACC[mi][ni] = __builtin_amdgcn_mfma_f32_16x16x32_bf16(AR[mi][kk], BR[ni][kk], ACC[mi][ni], 0, 0, 0);

// ------- 256x256 core with fragment read-ahead (proven r14/r15) -------------
__device__ __forceinline__ void gemm8p_core(
    const short* __restrict__ Ag, int lda,
    const short* __restrict__ Bg, int ldb,
    int m0, int n0, int nt, short* lds, f32x4 (&acc)[4][4][2])
{
    const int tid  = threadIdx.x;
    const int wave = tid >> 6, lane = tid & 63;
    const int wm = wave >> 2, wn = wave & 3;
    const int lm = lane & 15, lk = lane >> 4;
    const int srow8 = lane >> 3;
    const int scol  = (lane & 7) * 8;

    auto stage = [&](const short* G, int ldg, int row0, int half, int kt, int sb) {
        short* l0 = lds + sb + (size_t)((kt & 1) * 2 + half) * 8192;
#pragma unroll
        for (int q = 0; q < 2; ++q) {
            int chunk = wave * 2 + q;
            int r = chunk * 8 + srow8;
            int c = scol ^ ((r & 7) << 3);
            load_lds16(G + (size_t)(row0 + half * 128 + r) * ldg + kt * 64 + c,
                       l0 + chunk * 512);
        }
    };
    auto rdA = [&](int qa, int kt, int mi, int kk) -> short8 {
        int rl = wm * 64 + mi * 16 + lm;
        int c  = (kk * 32 + lk * 8) ^ ((rl & 7) << 3);
        return *(const short8*)(lds + (size_t)((kt & 1) * 2 + qa) * 8192 + rl * 64 + c);
    };
    auto rdB = [&](int qb, int kt, int ni, int kk) -> short8 {
        int rl = wn * 32 + ni * 16 + lm;
        int c  = (kk * 32 + lk * 8) ^ ((rl & 7) << 3);
        return *(const short8*)(lds + 32768 + (size_t)((kt & 1) * 2 + qb) * 8192 + rl * 64 + c);
    };

    stage(Ag, lda, m0, 0, 0, 0);
    stage(Bg, ldb, n0, 0, 0, 32768);
    stage(Bg, ldb, n0, 1, 0, 32768);
    stage(Ag, lda, m0, 1, 0, 0);
    stage(Ag, lda, m0, 0, 1, 0);
    stage(Bg, ldb, n0, 0, 1, 32768);
    stage(Bg, ldb, n0, 1, 1, 32768);
    stage(Ag, lda, m0, 1, 1, 0);
    WAIT_VM(12);
    BAR();

    short8 a0[4][2], a1[4][2], b0[2][2], b1[2][2], b0n[2][2];
#pragma unroll
    for (int mi = 0; mi < 4; ++mi) { a0[mi][0] = rdA(0, 0, mi, 0); a0[mi][1] = rdA(0, 0, mi, 1); }
#pragma unroll
    for (int ni = 0; ni < 2; ++ni) { b0[ni][0] = rdB(0, 0, ni, 0); b0[ni][1] = rdB(0, 0, ni, 1); }
    WAIT_VM(10);
    BAR();

    for (int t = 0; t < nt; ++t) {
        const bool st = (t + 2 < nt);
        const bool rd = (t + 1 < nt);
        // ---- P0 ----
#pragma unroll
        for (int ni = 0; ni < 2; ++ni) { b1[ni][0] = rdB(1, t, ni, 0); b1[ni][1] = rdB(1, t, ni, 1); }
        BAR();
        WAIT_LGKM(4);
        __builtin_amdgcn_s_setprio(1);
        MFMA16(a0, b0, acc[0]);
        __builtin_amdgcn_s_setprio(0);
        if (rd) { WAIT_VM(8); } else { WAIT_VM(0); }
        BAR();
        // ---- P1 ----
#pragma unroll
        for (int mi = 0; mi < 4; ++mi) { a1[mi][0] = rdA(1, t, mi, 0); a1[mi][1] = rdA(1, t, mi, 1); }
        if (st) { stage(Ag, lda, m0, 0, t + 2, 0); stage(Bg, ldb, n0, 0, t + 2, 32768); }
        BAR();
        WAIT_LGKM(8);
        __builtin_amdgcn_s_setprio(1);
        MFMA16(a0, b1, acc[1]);
        __builtin_amdgcn_s_setprio(0);
        BAR();
        // ---- P2 ----
        if (st) stage(Bg, ldb, n0, 1, t + 2, 32768);
        BAR();
        WAIT_LGKM0();
        __builtin_amdgcn_s_setprio(1);
        MFMA16(a1, b1, acc[3]);
        __builtin_amdgcn_s_setprio(0);
        if (st) { WAIT_VM(10); } else { WAIT_VM(0); }
        BAR();
        // ---- P3 ----
        if (rd) {
#pragma unroll
            for (int mi = 0; mi < 4; ++mi) { a0[mi][0] = rdA(0, t + 1, mi, 0); a0[mi][1] = rdA(0, t + 1, mi, 1); }
#pragma unroll
            for (int ni = 0; ni < 2; ++ni) { b0n[ni][0] = rdB(0, t + 1, ni, 0); b0n[ni][1] = rdB(0, t + 1, ni, 1); }
        }
        if (st) stage(Ag, lda, m0, 1, t + 2, 0);
        BAR();
        __builtin_amdgcn_s_setprio(1);
        MFMA16(a1, b0, acc[2]);
        __builtin_amdgcn_s_setprio(0);
        if (rd) {
#pragma unroll
            for (int ni = 0; ni < 2; ++ni) { b0[ni][0] = b0n[ni][0]; b0[ni][1] = b0n[ni][1]; }
            WAIT_VM(10);
        } else { WAIT_VM(0); }
        BAR();
    }
}

// forward: acc = A_u x B1''^T; epilogue: mix (x KF) + parity fold -> Ae|Ao
__global__ __launch_bounds__(512, 2) void k_fwd8(short* __restrict__ Wb)
{
    __shared__ short lds_s[65536];
    int xcd = blockIdx.x & 7, idx = blockIdx.x >> 3;
    const int m0 = (((xcd >> 1) << 2) + (idx >> 3)) * 256;
    const int n0 = (((xcd & 1) << 3) + (idx & 7)) * 256;
    const int tid = threadIdx.x;
    const int wave = tid >> 6, lane = tid & 63;
    const int wm = wave >> 2, wn = wave & 3;
    const int lm = lane & 15, lk = lane >> 4;

    f32x4 acc[4][4][2] = {};
    gemm8p_core(Wb + S_A, 2048, Wb + S_B1, 2048, m0, n0, 32, lds_s, acc);

    short* Uw = Wb + S_U;
    const short* KF = Wb + S_U;
    short (*M)[136] = (short(*)[136])lds_s;
    for (int q = 0; q < 4; ++q) {
        __syncthreads();
#pragma unroll
        for (int mi = 0; mi < 4; ++mi)
#pragma unroll
        for (int ni = 0; ni < 2; ++ni)
#pragma unroll
        for (int r = 0; r < 4; ++r)
            M[wm * 64 + mi * 16 + lk * 4 + r][wn * 32 + ni * 16 + lm] =
                f2bf(acc[q][mi][ni][r]);
        __syncthreads();
        const int pq0 = (n0 >> 2) + (q & 1) * 32;
        int rl = tid >> 2;
        int cp = (tid & 3) * 8;
        int rowg = m0 + (q >> 1) * 128 + rl;
        int h = rowg & (cH - 1);
        int colg = n0 + (q & 1) * 128 + cp * 4;
        short8 kf4[4], m4[4];
#pragma unroll
        for (int w = 0; w < 4; ++w) {
            kf4[w] = *(const short8*)&KF[(size_t)(4096 + h) * 4096 + colg + w * 8];
            m4[w]  = *(const short8*)&M[rl][cp * 4 + w * 8];
        }
        short8 vce, vse, vco, vso;
#pragma unroll
        for (int i = 0; i < 8; ++i) {
            int w = i >> 1, o = (i & 1) * 4;
            float C  = bf2f(m4[w][o]),   S  = bf2f(m4[w][o+1]);
            float C2 = bf2f(m4[w][o+2]), S2 = bf2f(m4[w][o+3]);
            float Ck  = bf2f(kf4[w][o]),   Sk  = bf2f(kf4[w][o+1]);
            float Ck2 = bf2f(kf4[w][o+2]), Sk2 = bf2f(kf4[w][o+3]);
            int pp = pq0 + cp + i;
            float scp = (pp == 0 ? 1.0f : 2.0f) * (1.0f / (float)M2);
            float scq = 2.0f / (float)M2;
            float yrp = scp * (Ck * C - Sk * S);
            float yip = scp * (Ck * S + Sk * C);
            float yrq = scq * (Ck2 * C2 - Sk2 * S2);
            float yiq = scq * (Ck2 * S2 + Sk2 * C2);
            float ce, co, se, so;
            if (pp == 0) { ce = yrp; co = yrp; se = yrq; so = yiq; }
            else { ce = yrp + yrq; co = yrp - yrq; se = yip - yiq; so = yip + yiq; }
            vce[i] = f2bf(ce); vco[i] = f2bf(co);
            vse[i] = f2bf(se); vso[i] = f2bf(so);
        }
        size_t base = (size_t)rowg * 4096;
        int kx = pq0 + cp;
        *(short8*)&Uw[base + kx]        = vce;
        *(short8*)&Uw[base + 1024 + kx] = vse;
        *(short8*)&Uw[base + 2048 + kx] = vco;
        *(short8*)&Uw[base + 3072 + kx] = vso;
    }
}

// KF rows: U[4096+h] = A_k x B1''^T ; 64x128 tiles, grid (32,8) = 256 blocks
__global__ __launch_bounds__(256, 2) void k_kfg(short* __restrict__ Wb)
{
    __shared__ __align__(16) short As[64][32];
    __shared__ __align__(16) short Bs[128][32];
    const short* A = Wb + S_A;
    const short* B = Wb + S_B1;
    short* U = Wb + S_U;
    const int tid = threadIdx.x;
    const int m0 = 4096 + blockIdx.y * 64, n0 = blockIdx.x * 128;
    const int wave = tid >> 6, lane = tid & 63;
    const int wr = wave >> 1, wc = wave & 1;
    const int lm = lane & 15, lk = lane >> 4;
    const int srowA = tid >> 2,  scolA = (tid & 3) * 8;
    const int srowB = lane >> 2, scolB = (lane & 3) * 8;

    f32x4 acc[2][4] = {};
    for (int k0 = 0; k0 < 2048; k0 += 32) {
        __syncthreads();
        load_lds16(&A[(size_t)(m0 + srowA) * 2048 + k0 + scolA],
                   &As[0][0] + wave * 512);
#pragma unroll
        for (int q = 0; q < 2; ++q) {
            int chunk = wave * 2 + q;
            load_lds16(&B[(size_t)(n0 + chunk * 16 + srowB) * 2048 + k0 + scolB],
                       &Bs[chunk * 16][0]);
        }
        __syncthreads();
        short8 a[2];
#pragma unroll
        for (int mi = 0; mi < 2; ++mi)
            a[mi] = *(const short8*)&As[wr*32 + mi*16 + lm][lk*8];
#pragma unroll
        for (int ni = 0; ni < 4; ++ni) {
            short8 b = *(const short8*)&Bs[wc*64 + ni*16 + lm][lk*8];
#pragma unroll
            for (int mi = 0; mi < 2; ++mi)
                acc[mi][ni] = __builtin_amdgcn_mfma_f32_16x16x32_bf16(a[mi], b, acc[mi][ni], 0, 0, 0);
        }
    }
#pragma unroll
    for (int mi = 0; mi < 2; ++mi)
#pragma unroll
    for (int ni = 0; ni < 4; ++ni)
#pragma unroll
    for (int r = 0; r < 4; ++r) {
        int row = m0 + wr*32 + mi*16 + lk*4 + r;
        int col = n0 + wc*64 + ni*16 + lm;
        U[(size_t)row * 4096 + col] = f2bf(acc[mi][ni][r]);
    }
}

// inverse: per parity p, y[2tau+p] = A(e/o) x B2_p^T, K=2048, BM=256 x BN=128
__global__ __launch_bounds__(512, 1) void k_invB(const float* __restrict__ u,
                                                 const float* __restrict__ Dp,
                                                 short* __restrict__ Wb,
                                                 float* __restrict__ out)
{
    __shared__ short lds_s[57344];   // 112 KB
    int xcd = blockIdx.x & 7, idx = blockIdx.x >> 3;
    const int m0 = ((((xcd >> 1) << 2) + (idx >> 3))) * 256;   // bh
    const int nj = ((xcd & 1) << 3) + (idx & 7);               // 0..15
    const int p  = nj >> 3;
    const int n0 = (nj & 7) * 128;                             // tau0
    const int tid = threadIdx.x;
    const int wave = tid >> 6, lane = tid & 63;
    const int wm = wave >> 2, wn = wave & 3;
    const int lm = lane & 15, lk = lane >> 4;
    const int srow8 = lane >> 3;
    const int scol  = (lane & 7) * 8;
    constexpr int nt = 32;
    short* lds = lds_s;
    const short* Ag = Wb + S_U + (size_t)p * 2048;
    const short* Bg = Wb + S_T2 + (size_t)p * 1024 * 2048;

    auto stageA = [&](int half, int kt) {
        short* l0 = lds + (size_t)((kt & 1) * 2 + half) * 8192;
#pragma unroll
        for (int q = 0; q < 2; ++q) {
            int chunk = wave * 2 + q;
            int r = chunk * 8 + srow8;
            int c = scol ^ ((r & 7) << 3);
            load_lds16(Ag + (size_t)(m0 + half * 128 + r) * 4096 + kt * 64 + c,
                       l0 + chunk * 512);
        }
    };
    auto stageB = [&](int kt, int slot) {
        short* l0 = lds + 32768 + (size_t)slot * 8192;
#pragma unroll
        for (int q = 0; q < 2; ++q) {
            int chunk = wave * 2 + q;
            int r = chunk * 8 + srow8;
            int c = scol ^ ((r & 7) << 3);
            load_lds16(Bg + (size_t)(n0 + r) * 2048 + kt * 64 + c,
                       l0 + chunk * 512);
        }
    };
    auto rdA = [&](int half, int kt, int mi, int kk) -> short8 {
        int rl = wm * 64 + mi * 16 + lm;
        int c  = (kk * 32 + lk * 8) ^ ((rl & 7) << 3);
        return *(const short8*)(lds + (size_t)((kt & 1) * 2 + half) * 8192 + rl * 64 + c);
    };
    auto rdB = [&](int slot, int ni, int kk) -> short8 {
        int rl = wn * 32 + ni * 16 + lm;
        int c  = (kk * 32 + lk * 8) ^ ((rl & 7) << 3);
        return *(const short8*)(lds + 32768 + (size_t)slot * 8192 + rl * 64 + c);
    };

    f32x4 acc[2][4][2] = {};

    stageA(0, 0);
    stageB(0, 0);
    stageA(1, 0);
    stageA(0, 1);
    stageB(1, 1);
    stageB(2, 2);
    WAIT_VM(8);
    BAR();
    short8 a0[4][2], a1[4][2], b[2][2], bn[2][2];
#pragma unroll
    for (int mi = 0; mi < 4; ++mi) { a0[mi][0] = rdA(0, 0, mi, 0); a0[mi][1] = rdA(0, 0, mi, 1); }
#pragma unroll
    for (int ni = 0; ni < 2; ++ni) { b[ni][0] = rdB(0, ni, 0); b[ni][1] = rdB(0, ni, 1); }
    WAIT_VM(4);
    BAR();

    int bs = 0;
    for (int t = 0; t < nt; ++t) {
        const bool r1 = (t + 1 < nt);
        const bool s2 = (t + 2 < nt);
        const bool s3 = (t + 3 < nt);
        const bool tail = (t >= nt - 3);
        const int bs2 = (bs == 2) ? 0 : bs + 1;
        // ---- P0 ----
#pragma unroll
        for (int mi = 0; mi < 4; ++mi) { a1[mi][0] = rdA(1, t, mi, 0); a1[mi][1] = rdA(1, t, mi, 1); }
        if (r1) stageA(1, t + 1);
        BAR();
        WAIT_LGKM(8);
        __builtin_amdgcn_s_setprio(1);
        MFMA16(a0, b, acc[0]);
        __builtin_amdgcn_s_setprio(0);
        if (tail) { WAIT_VM(0); } else { WAIT_VM(4); }
        BAR();
        // ---- P1 ----
        if (r1) {
#pragma unroll
            for (int mi = 0; mi < 4; ++mi) { a0[mi][0] = rdA(0, t + 1, mi, 0); a0[mi][1] = rdA(0, t + 1, mi, 1); }
#pragma unroll
            for (int ni = 0; ni < 2; ++ni) { bn[ni][0] = rdB(bs2, ni, 0); bn[ni][1] = rdB(bs2, ni, 1); }
        }
        if (s2) stageA(0, t + 2);
        if (s3) stageB(t + 3, bs);
        BAR();
        if (r1) { WAIT_LGKM(12); } else { WAIT_LGKM0(); }
        __builtin_amdgcn_s_setprio(1);
        MFMA16(a1, b, acc[1]);
        __builtin_amdgcn_s_setprio(0);
        if (r1) {
#pragma unroll
            for (int ni = 0; ni < 2; ++ni) { b[ni][0] = bn[ni][0]; b[ni][1] = bn[ni][1]; }
        }
        if (tail) { WAIT_VM(0); } else { WAIT_VM(4); }
        BAR();
        bs = bs2;
    }

    const int b_  = m0 >> 9;
    const int h00 = m0 & 511;
    float (*T)[132] = (float(*)[132])lds_s;
#pragma unroll
    for (int q = 0; q < 2; ++q) {
        __syncthreads();
#pragma unroll
        for (int mi = 0; mi < 4; ++mi)
#pragma unroll
        for (int ni = 0; ni < 2; ++ni) {
            int tl = wn * 32 + ni * 16 + lm;
            int hl = wm * 64 + mi * 16 + lk * 4;
            *(float4*)&T[tl][hl] = *(float4*)&acc[q][mi][ni];
        }
        __syncthreads();
        int hg = h00 + q * 128 + (tid & 31) * 4;
        float4 dv = *(const float4*)&Dp[hg];
#pragma unroll
        for (int it = 0; it < 8; ++it) {
            int tl = (tid >> 5) + it * 16;
            int tg = 2 * (n0 + tl) + p;
            size_t gidx = ((size_t)b_ * cL + tg) * cH + hg;
            float4 uv = *(const float4*)&u[gidx];
            float4 yv = *(float4*)&T[tl][(tid & 31) * 4];
            yv.x += dv.x * uv.x;
            yv.y += dv.y * uv.y;
            yv.z += dv.z * uv.z;
            yv.w += dv.w * uv.w;
            *(float4*)&out[gidx] = yv;
        }
    }
}

extern "C" void kernel_launch(void* const* d_in, const int* in_sizes, int n_in,
                              void* d_out, int out_size, void* d_ws, size_t ws_size,
                              hipStream_t stream) {
    const float* u    = (const float*)d_in[0];
    const float* w_re = (const float*)d_in[1];
    const float* w_im = (const float*)d_in[2];
    const float* C_re = (const float*)d_in[3];
    const float* C_im = (const float*)d_in[4];
    const float* Dp   = (const float*)d_in[5];
    const float* dt   = (const float*)d_in[6];
    float* out = (float*)d_out;
    short* Wb  = (short*)d_ws;

    hipLaunchKernelGGL(k_tabs,  dim3(4096), dim3(256), 0, stream, Wb);
    hipLaunchKernelGGL(k_trans, dim3(cL / 64, cH / 64, cB), dim3(256), 0, stream, u, Wb);
    hipLaunchKernelGGL(k_kgen,  dim3(cH), dim3(256), 0, stream,
                       w_re, w_im, C_re, C_im, dt, Wb);
    hipLaunchKernelGGL(k_kfg,   dim3(32, 8), dim3(256), 0, stream, Wb);
    hipLaunchKernelGGL(k_fwd8,  dim3(256), dim3(512), 0, stream, Wb);
    hipLaunchKernelGGL(k_invB,  dim3(256), dim3(512), 0, stream, u, Dp, Wb, out);
}

// Round 18
// 190.938 us; speedup vs baseline: 1.0380x; 1.0023x over previous
//
#include <hip/hip_runtime.h>
#include <hip/hip_bf16.h>
#include <math.h>

// S4DConv via MFMA: B=8, L=2048, H=512, N=64, CH=1
//   r18 = r17 with fwd8 core vmcnt density reduced 3/tile -> 2/tile:
//   waits now {P2: vm(10), P3: vm(8)} (ledger: S3(t-2) retired before P1(t)
//   reads a1(t); S2(t-2) before P0 reads b1(t)). All else byte-identical.

namespace {
constexpr int cB = 8;
constexpr int cL = 2048;
constexpr int cH = 512;
constexpr int cN = 64;
constexpr int M1 = 4095;
constexpr int M2 = 4096;
constexpr int BH = cB * cH;            // 4096
constexpr int MA = BH + cH;            // 4608

constexpr size_t S0   = 2 * ((size_t)cH * cN * 6);
constexpr size_t S_B1 = S0;                           // [4096][2048] paired
constexpr size_t S_A  = S_B1 + (size_t)4096 * 2048;   // [4608][2048]
constexpr size_t S_T2 = S_A  + (size_t)MA * 2048;     // B2 [2][1024][2048]
constexpr size_t S_U  = S_T2 + (size_t)2048 * 4096;   // [4608][4096]: rows<4096 Ae|Ao; 4096+ KF
}

typedef __attribute__((ext_vector_type(8))) short short8;
typedef __attribute__((ext_vector_type(4))) float f32x4;

static __device__ inline short f2bf(float x) {
    __hip_bfloat16 h = __float2bfloat16(x);
    return *reinterpret_cast<short*>(&h);
}
static __device__ inline float bf2f(short s) {
    return __uint_as_float(((unsigned int)(unsigned short)s) << 16);
}
static __device__ __forceinline__ void load_lds16(const short* g, short* l) {
    __builtin_amdgcn_global_load_lds(
        (const __attribute__((address_space(1))) void*)g,
        (__attribute__((address_space(3))) void*)l, 16, 0, 0);
}
#define WAIT_LGKM0() do { asm volatile("s_waitcnt lgkmcnt(0)" ::: "memory"); \
                          __builtin_amdgcn_sched_barrier(0); } while (0)
#define WAIT_LGKM(n) do { asm volatile("s_waitcnt lgkmcnt(" #n ")" ::: "memory"); \
                          __builtin_amdgcn_sched_barrier(0); } while (0)
#define WAIT_VM(n)   do { asm volatile("s_waitcnt vmcnt(" #n ")" ::: "memory"); \
                          __builtin_amdgcn_sched_barrier(0); } while (0)
#define BAR() __builtin_amdgcn_s_barrier()

__global__ __launch_bounds__(256) void k_tabs(short* __restrict__ Wb)
{
    int tid = threadIdx.x;
    if (blockIdx.x < 2048) {              // B1'' rows for DFT j
        int j  = blockIdx.x;
        int base = (j < 1024) ? 4 * j : (j == 1024 ? 2 : 4 * (2048 - j) + 2);
        int t0 = tid * 8;
        int p0 = (int)(((long)j * t0) % M1);
        float c, s, cs, ss;
        sincosf((6.283185307179586f / (float)M1) * (float)p0, &s, &c);
        sincosf((6.283185307179586f / (float)M1) * (float)j,  &ss, &cs);
        short8 vc, vs;
#pragma unroll
        for (int i = 0; i < 8; ++i) {
            vc[i] = f2bf(c); vs[i] = f2bf(s);
            float tr = c * cs - s * ss;
            s = c * ss + s * cs;
            c = tr;
        }
        *(short8*)&Wb[S_B1 + (size_t)base       * 2048 + t0] = vc;
        *(short8*)&Wb[S_B1 + (size_t)(base + 1) * 2048 + t0] = vs;
    } else {                              // B2 parity rows
        int r   = blockIdx.x - 2048;
        int p   = r >> 10, tau = r & 1023;
        int t   = 2 * tau + p;
        int k0  = tid * 8;
        float stepang = (6.283185307179586f / (float)M2) * (float)t;
        float cs, ss; sincosf(stepang, &ss, &cs);
        short8 v;
        if (k0 < 1024) {
            int ph = (k0 * t) & (M2 - 1);
            float c, s; sincosf((6.283185307179586f / (float)M2) * (float)ph, &s, &c);
#pragma unroll
            for (int i = 0; i < 8; ++i) {
                v[i] = f2bf(c);
                float tr = c * cs - s * ss;
                s = c * ss + s * cs;
                c = tr;
            }
        } else {
            int j0 = k0 - 1024;
            int ph = (j0 * t) & (M2 - 1);
            float c, s; sincosf((6.283185307179586f / (float)M2) * (float)ph, &s, &c);
#pragma unroll
            for (int i = 0; i < 8; ++i) {
                int k = k0 + i;
                v[i] = (k == 1024) ? f2bf((tau & 1) ? -1.f : 1.f) : f2bf(s);
                float tr = c * cs - s * ss;
                s = c * ss + s * cs;
                c = tr;
            }
        }
        *(short8*)&Wb[S_T2 + (size_t)r * 2048 + k0] = v;
    }
}

__global__ __launch_bounds__(256) void k_trans(const float* __restrict__ u,
                                               short* __restrict__ Wb)
{
    __shared__ float tile[64][65];
    int t0 = blockIdx.x * 64;
    int h0 = blockIdx.y * 64;
    int b  = blockIdx.z;
    int cx = threadIdx.x & 63, r0 = threadIdx.x >> 6;
#pragma unroll
    for (int i = 0; i < 16; ++i) {
        int row = r0 + i * 4;
        tile[row][cx] = u[((size_t)b * cL + t0 + row) * cH + h0 + cx];
    }
    __syncthreads();
    short* A = Wb + S_A;
#pragma unroll
    for (int i = 0; i < 16; ++i) {
        int hrow = r0 + i * 4;
        A[(size_t)(b * cH + h0 + hrow) * 2048 + t0 + cx] = f2bf(tile[cx][hrow]);
    }
}

__global__ __launch_bounds__(256) void k_kgen(
    const float* __restrict__ w_re, const float* __restrict__ w_im,
    const float* __restrict__ C_re, const float* __restrict__ C_im,
    const float* __restrict__ dt, short* __restrict__ Wb)
{
    __shared__ float md[cN * 6];
    int h = blockIdx.x, tid = threadIdx.x;
    if (tid < cN) {
        int idx = h * cN + tid;
        double dtv = dt[h];
        double wr = w_re[idx], wi = w_im[idx];
        double ar = wr * dtv, ai = wi * dtv;
        double er = exp(ar);
        double zs, zc; sincos(ai, &zs, &zc);
        double zr = er * zc, zi = er * zs;
        double nr = zr - 1.0, ni = zi;
        double inv = 1.0 / (wr * wr + wi * wi);
        double gr = (nr * wr + ni * wi) * inv;
        double gi = (ni * wr - nr * wi) * inv;
        double cr = C_re[idx], ci = C_im[idx];
        md[tid*6+0] = (float)(cr * gr - ci * gi);
        md[tid*6+1] = (float)(cr * gi + ci * gr);
        md[tid*6+2] = (float)zr; md[tid*6+3] = (float)zi;
        md[tid*6+4] = (float)ar; md[tid*6+5] = (float)ai;
    }
    __syncthreads();
    int t0 = tid * 8;
    float acc[8] = {0.f, 0.f, 0.f, 0.f, 0.f, 0.f, 0.f, 0.f};
    for (int n = 0; n < cN; ++n) {
        float csr = md[n*6+0], csi = md[n*6+1];
        float zr  = md[n*6+2], zi  = md[n*6+3];
        float ar  = md[n*6+4], ai  = md[n*6+5];
        float mag = expf(ar * (float)t0);
        double ph = fmod((double)ai * (double)t0, 6.283185307179586);
        float s, c; sincosf((float)ph, &s, &c);
        float pr = mag * c, pi = mag * s;
#pragma unroll
        for (int i = 0; i < 8; ++i) {
            acc[i] += csr * pr - csi * pi;
            float tr = pr * zr - pi * zi;
            pi = pr * zi + pi * zr;
            pr = tr;
        }
    }
    short8 v;
#pragma unroll
    for (int i = 0; i < 8; ++i) v[i] = f2bf(2.f * acc[i]);
    *reinterpret_cast<short8*>(&Wb[S_A + (size_t)(BH + h) * 2048 + t0]) = v;
}

#define MFMA16(AR, BR, ACC) \
    _Pragma("unroll") for (int kk = 0; kk < 2; ++kk) \
    _Pragma("unroll") for (int ni = 0; ni < 2; ++ni) \
    _Pragma("unroll") for (int mi = 0; mi < 4; ++mi) \
        ACC[mi][ni] = __builtin_amdgcn_mfma_f32_16x16x32_bf16(AR[mi][kk], BR[ni][kk], ACC[mi][ni], 0, 0, 0);

// ------- 256x256 core, read-ahead, 2 vmcnt/tile {P2:vm10, P3:vm8} -----------
__device__ __forceinline__ void gemm8p_core(
    const short* __restrict__ Ag, int lda,
    const short* __restrict__ Bg, int ldb,
    int m0, int n0, int nt, short* lds, f32x4 (&acc)[4][4][2])
{
    const int tid  = threadIdx.x;
    const int wave = tid >> 6, lane = tid & 63;
    const int wm = wave >> 2, wn = wave & 3;
    const int lm = lane & 15, lk = lane >> 4;
    const int srow8 = lane >> 3;
    const int scol  = (lane & 7) * 8;

    auto stage = [&](const short* G, int ldg, int row0, int half, int kt, int sb) {
        short* l0 = lds + sb + (size_t)((kt & 1) * 2 + half) * 8192;
#pragma unroll
        for (int q = 0; q < 2; ++q) {
            int chunk = wave * 2 + q;
            int r = chunk * 8 + srow8;
            int c = scol ^ ((r & 7) << 3);
            load_lds16(G + (size_t)(row0 + half * 128 + r) * ldg + kt * 64 + c,
                       l0 + chunk * 512);
        }
    };
    auto rdA = [&](int qa, int kt, int mi, int kk) -> short8 {
        int rl = wm * 64 + mi * 16 + lm;
        int c  = (kk * 32 + lk * 8) ^ ((rl & 7) << 3);
        return *(const short8*)(lds + (size_t)((kt & 1) * 2 + qa) * 8192 + rl * 64 + c);
    };
    auto rdB = [&](int qb, int kt, int ni, int kk) -> short8 {
        int rl = wn * 32 + ni * 16 + lm;
        int c  = (kk * 32 + lk * 8) ^ ((rl & 7) << 3);
        return *(const short8*)(lds + 32768 + (size_t)((kt & 1) * 2 + qb) * 8192 + rl * 64 + c);
    };

    stage(Ag, lda, m0, 0, 0, 0);
    stage(Bg, ldb, n0, 0, 0, 32768);
    stage(Bg, ldb, n0, 1, 0, 32768);
    stage(Ag, lda, m0, 1, 0, 0);
    stage(Ag, lda, m0, 0, 1, 0);
    stage(Bg, ldb, n0, 0, 1, 32768);
    stage(Bg, ldb, n0, 1, 1, 32768);
    stage(Ag, lda, m0, 1, 1, 0);
    WAIT_VM(12);
    BAR();

    short8 a0[4][2], a1[4][2], b0[2][2], b1[2][2], b0n[2][2];
#pragma unroll
    for (int mi = 0; mi < 4; ++mi) { a0[mi][0] = rdA(0, 0, mi, 0); a0[mi][1] = rdA(0, 0, mi, 1); }
#pragma unroll
    for (int ni = 0; ni < 2; ++ni) { b0[ni][0] = rdB(0, 0, ni, 0); b0[ni][1] = rdB(0, 0, ni, 1); }
    WAIT_VM(8);                  // B1(0), A1(0) landed
    BAR();

    for (int t = 0; t < nt; ++t) {
        const bool st = (t + 2 < nt);
        const bool rd = (t + 1 < nt);
        // ---- P0: rd-ahead b1(t); MFMA Q00(a0,b0) ----
#pragma unroll
        for (int ni = 0; ni < 2; ++ni) { b1[ni][0] = rdB(1, t, ni, 0); b1[ni][1] = rdB(1, t, ni, 1); }
        BAR();
        WAIT_LGKM(4);
        __builtin_amdgcn_s_setprio(1);
        MFMA16(a0, b0, acc[0]);
        __builtin_amdgcn_s_setprio(0);
        BAR();
        // ---- P1: rd-ahead a1(t); stage A0,B0(t+2); MFMA Q01(a0,b1) ----
#pragma unroll
        for (int mi = 0; mi < 4; ++mi) { a1[mi][0] = rdA(1, t, mi, 0); a1[mi][1] = rdA(1, t, mi, 1); }
        if (st) { stage(Ag, lda, m0, 0, t + 2, 0); stage(Bg, ldb, n0, 0, t + 2, 32768); }
        BAR();
        WAIT_LGKM(8);
        __builtin_amdgcn_s_setprio(1);
        MFMA16(a0, b1, acc[1]);
        __builtin_amdgcn_s_setprio(0);
        BAR();
        // ---- P2: stage B1(t+2); MFMA Q11(a1,b1) ----
        if (st) stage(Bg, ldb, n0, 1, t + 2, 32768);
        BAR();
        WAIT_LGKM0();
        __builtin_amdgcn_s_setprio(1);
        MFMA16(a1, b1, acc[3]);
        __builtin_amdgcn_s_setprio(0);
        if (st) { WAIT_VM(10); } else { WAIT_VM(0); }
        BAR();
        // ---- P3: rd-ahead a0,b0n(t+1); stage A1(t+2); MFMA Q10(a1,b0) ----
        if (rd) {
#pragma unroll
            for (int mi = 0; mi < 4; ++mi) { a0[mi][0] = rdA(0, t + 1, mi, 0); a0[mi][1] = rdA(0, t + 1, mi, 1); }
#pragma unroll
            for (int ni = 0; ni < 2; ++ni) { b0n[ni][0] = rdB(0, t + 1, ni, 0); b0n[ni][1] = rdB(0, t + 1, ni, 1); }
        }
        if (st) stage(Ag, lda, m0, 1, t + 2, 0);
        BAR();
        __builtin_amdgcn_s_setprio(1);
        MFMA16(a1, b0, acc[2]);
        __builtin_amdgcn_s_setprio(0);
        if (rd) {
#pragma unroll
            for (int ni = 0; ni < 2; ++ni) { b0[ni][0] = b0n[ni][0]; b0[ni][1] = b0n[ni][1]; }
            WAIT_VM(8);          // retires S3(t-1): A1(t+1) ready for P1(t+1)
        } else { WAIT_VM(0); }
        BAR();
    }
}

// forward: acc = A_u x B1''^T; epilogue: mix (x KF) + parity fold -> Ae|Ao
__global__ __launch_bounds__(512, 2) void k_fwd8(short* __restrict__ Wb)
{
    __shared__ short lds_s[65536];
    int xcd = blockIdx.x & 7, idx = blockIdx.x >> 3;
    const int m0 = (((xcd >> 1) << 2) + (idx >> 3)) * 256;
    const int n0 = (((xcd & 1) << 3) + (idx & 7)) * 256;
    const int tid = threadIdx.x;
    const int wave = tid >> 6, lane = tid & 63;
    const int wm = wave >> 2, wn = wave & 3;
    const int lm = lane & 15, lk = lane >> 4;

    f32x4 acc[4][4][2] = {};
    gemm8p_core(Wb + S_A, 2048, Wb + S_B1, 2048, m0, n0, 32, lds_s, acc);

    short* Uw = Wb + S_U;
    const short* KF = Wb + S_U;
    short (*M)[136] = (short(*)[136])lds_s;
    for (int q = 0; q < 4; ++q) {
        __syncthreads();
#pragma unroll
        for (int mi = 0; mi < 4; ++mi)
#pragma unroll
        for (int ni = 0; ni < 2; ++ni)
#pragma unroll
        for (int r = 0; r < 4; ++r)
            M[wm * 64 + mi * 16 + lk * 4 + r][wn * 32 + ni * 16 + lm] =
                f2bf(acc[q][mi][ni][r]);
        __syncthreads();
        const int pq0 = (n0 >> 2) + (q & 1) * 32;
        int rl = tid >> 2;
        int cp = (tid & 3) * 8;
        int rowg = m0 + (q >> 1) * 128 + rl;
        int h = rowg & (cH - 1);
        int colg = n0 + (q & 1) * 128 + cp * 4;
        short8 kf4[4], m4[4];
#pragma unroll
        for (int w = 0; w < 4; ++w) {
            kf4[w] = *(const short8*)&KF[(size_t)(4096 + h) * 4096 + colg + w * 8];
            m4[w]  = *(const short8*)&M[rl][cp * 4 + w * 8];
        }
        short8 vce, vse, vco, vso;
#pragma unroll
        for (int i = 0; i < 8; ++i) {
            int w = i >> 1, o = (i & 1) * 4;
            float C  = bf2f(m4[w][o]),   S  = bf2f(m4[w][o+1]);
            float C2 = bf2f(m4[w][o+2]), S2 = bf2f(m4[w][o+3]);
            float Ck  = bf2f(kf4[w][o]),   Sk  = bf2f(kf4[w][o+1]);
            float Ck2 = bf2f(kf4[w][o+2]), Sk2 = bf2f(kf4[w][o+3]);
            int pp = pq0 + cp + i;
            float scp = (pp == 0 ? 1.0f : 2.0f) * (1.0f / (float)M2);
            float scq = 2.0f / (float)M2;
            float yrp = scp * (Ck * C - Sk * S);
            float yip = scp * (Ck * S + Sk * C);
            float yrq = scq * (Ck2 * C2 - Sk2 * S2);
            float yiq = scq * (Ck2 * S2 + Sk2 * C2);
            float ce, co, se, so;
            if (pp == 0) { ce = yrp; co = yrp; se = yrq; so = yiq; }
            else { ce = yrp + yrq; co = yrp - yrq; se = yip - yiq; so = yip + yiq; }
            vce[i] = f2bf(ce); vco[i] = f2bf(co);
            vse[i] = f2bf(se); vso[i] = f2bf(so);
        }
        size_t base = (size_t)rowg * 4096;
        int kx = pq0 + cp;
        *(short8*)&Uw[base + kx]        = vce;
        *(short8*)&Uw[base + 1024 + kx] = vse;
        *(short8*)&Uw[base + 2048 + kx] = vco;
        *(short8*)&Uw[base + 3072 + kx] = vso;
    }
}

// KF rows: U[4096+h] = A_k x B1''^T ; 64x128 tiles, grid (32,8) = 256 blocks
__global__ __launch_bounds__(256, 2) void k_kfg(short* __restrict__ Wb)
{
    __shared__ __align__(16) short As[64][32];
    __shared__ __align__(16) short Bs[128][32];
    const short* A = Wb + S_A;
    const short* B = Wb + S_B1;
    short* U = Wb + S_U;
    const int tid = threadIdx.x;
    const int m0 = 4096 + blockIdx.y * 64, n0 = blockIdx.x * 128;
    const int wave = tid >> 6, lane = tid & 63;
    const int wr = wave >> 1, wc = wave & 1;
    const int lm = lane & 15, lk = lane >> 4;
    const int srowA = tid >> 2,  scolA = (tid & 3) * 8;
    const int srowB = lane >> 2, scolB = (lane & 3) * 8;

    f32x4 acc[2][4] = {};
    for (int k0 = 0; k0 < 2048; k0 += 32) {
        __syncthreads();
        load_lds16(&A[(size_t)(m0 + srowA) * 2048 + k0 + scolA],
                   &As[0][0] + wave * 512);
#pragma unroll
        for (int q = 0; q < 2; ++q) {
            int chunk = wave * 2 + q;
            load_lds16(&B[(size_t)(n0 + chunk * 16 + srowB) * 2048 + k0 + scolB],
                       &Bs[chunk * 16][0]);
        }
        __syncthreads();
        short8 a[2];
#pragma unroll
        for (int mi = 0; mi < 2; ++mi)
            a[mi] = *(const short8*)&As[wr*32 + mi*16 + lm][lk*8];
#pragma unroll
        for (int ni = 0; ni < 4; ++ni) {
            short8 b = *(const short8*)&Bs[wc*64 + ni*16 + lm][lk*8];
#pragma unroll
            for (int mi = 0; mi < 2; ++mi)
                acc[mi][ni] = __builtin_amdgcn_mfma_f32_16x16x32_bf16(a[mi], b, acc[mi][ni], 0, 0, 0);
        }
    }
#pragma unroll
    for (int mi = 0; mi < 2; ++mi)
#pragma unroll
    for (int ni = 0; ni < 4; ++ni)
#pragma unroll
    for (int r = 0; r < 4; ++r) {
        int row = m0 + wr*32 + mi*16 + lk*4 + r;
        int col = n0 + wc*64 + ni*16 + lm;
        U[(size_t)row * 4096 + col] = f2bf(acc[mi][ni][r]);
    }
}

// inverse: per parity p, y[2tau+p] = A(e/o) x B2_p^T, K=2048, BM=256 x BN=128
__global__ __launch_bounds__(512, 1) void k_invB(const float* __restrict__ u,
                                                 const float* __restrict__ Dp,
                                                 short* __restrict__ Wb,
                                                 float* __restrict__ out)
{
    __shared__ short lds_s[57344];   // 112 KB
    int xcd = blockIdx.x & 7, idx = blockIdx.x >> 3;
    const int m0 = ((((xcd >> 1) << 2) + (idx >> 3))) * 256;   // bh
    const int nj = ((xcd & 1) << 3) + (idx & 7);               // 0..15
    const int p  = nj >> 3;
    const int n0 = (nj & 7) * 128;                             // tau0
    const int tid = threadIdx.x;
    const int wave = tid >> 6, lane = tid & 63;
    const int wm = wave >> 2, wn = wave & 3;
    const int lm = lane & 15, lk = lane >> 4;
    const int srow8 = lane >> 3;
    const int scol  = (lane & 7) * 8;
    constexpr int nt = 32;
    short* lds = lds_s;
    const short* Ag = Wb + S_U + (size_t)p * 2048;
    const short* Bg = Wb + S_T2 + (size_t)p * 1024 * 2048;

    auto stageA = [&](int half, int kt) {
        short* l0 = lds + (size_t)((kt & 1) * 2 + half) * 8192;
#pragma unroll
        for (int q = 0; q < 2; ++q) {
            int chunk = wave * 2 + q;
            int r = chunk * 8 + srow8;
            int c = scol ^ ((r & 7) << 3);
            load_lds16(Ag + (size_t)(m0 + half * 128 + r) * 4096 + kt * 64 + c,
                       l0 + chunk * 512);
        }
    };
    auto stageB = [&](int kt, int slot) {
        short* l0 = lds + 32768 + (size_t)slot * 8192;
#pragma unroll
        for (int q = 0; q < 2; ++q) {
            int chunk = wave * 2 + q;
            int r = chunk * 8 + srow8;
            int c = scol ^ ((r & 7) << 3);
            load_lds16(Bg + (size_t)(n0 + r) * 2048 + kt * 64 + c,
                       l0 + chunk * 512);
        }
    };
    auto rdA = [&](int half, int kt, int mi, int kk) -> short8 {
        int rl = wm * 64 + mi * 16 + lm;
        int c  = (kk * 32 + lk * 8) ^ ((rl & 7) << 3);
        return *(const short8*)(lds + (size_t)((kt & 1) * 2 + half) * 8192 + rl * 64 + c);
    };
    auto rdB = [&](int slot, int ni, int kk) -> short8 {
        int rl = wn * 32 + ni * 16 + lm;
        int c  = (kk * 32 + lk * 8) ^ ((rl & 7) << 3);
        return *(const short8*)(lds + 32768 + (size_t)slot * 8192 + rl * 64 + c);
    };

    f32x4 acc[2][4][2] = {};

    stageA(0, 0);
    stageB(0, 0);
    stageA(1, 0);
    stageA(0, 1);
    stageB(1, 1);
    stageB(2, 2);
    WAIT_VM(8);
    BAR();
    short8 a0[4][2], a1[4][2], b[2][2], bn[2][2];
#pragma unroll
    for (int mi = 0; mi < 4; ++mi) { a0[mi][0] = rdA(0, 0, mi, 0); a0[mi][1] = rdA(0, 0, mi, 1); }
#pragma unroll
    for (int ni = 0; ni < 2; ++ni) { b[ni][0] = rdB(0, ni, 0); b[ni][1] = rdB(0, ni, 1); }
    WAIT_VM(4);
    BAR();

    int bs = 0;
    for (int t = 0; t < nt; ++t) {
        const bool r1 = (t + 1 < nt);
        const bool s2 = (t + 2 < nt);
        const bool s3 = (t + 3 < nt);
        const bool tail = (t >= nt - 3);
        const int bs2 = (bs == 2) ? 0 : bs + 1;
        // ---- P0 ----
#pragma unroll
        for (int mi = 0; mi < 4; ++mi) { a1[mi][0] = rdA(1, t, mi, 0); a1[mi][1] = rdA(1, t, mi, 1); }
        if (r1) stageA(1, t + 1);
        BAR();
        WAIT_LGKM(8);
        __builtin_amdgcn_s_setprio(1);
        MFMA16(a0, b, acc[0]);
        __builtin_amdgcn_s_setprio(0);
        if (tail) { WAIT_VM(0); } else { WAIT_VM(4); }
        BAR();
        // ---- P1 ----
        if (r1) {
#pragma unroll
            for (int mi = 0; mi < 4; ++mi) { a0[mi][0] = rdA(0, t + 1, mi, 0); a0[mi][1] = rdA(0, t + 1, mi, 1); }
#pragma unroll
            for (int ni = 0; ni < 2; ++ni) { bn[ni][0] = rdB(bs2, ni, 0); bn[ni][1] = rdB(bs2, ni, 1); }
        }
        if (s2) stageA(0, t + 2);
        if (s3) stageB(t + 3, bs);
        BAR();
        if (r1) { WAIT_LGKM(12); } else { WAIT_LGKM0(); }
        __builtin_amdgcn_s_setprio(1);
        MFMA16(a1, b, acc[1]);
        __builtin_amdgcn_s_setprio(0);
        if (r1) {
#pragma unroll
            for (int ni = 0; ni < 2; ++ni) { b[ni][0] = bn[ni][0]; b[ni][1] = bn[ni][1]; }
        }
        if (tail) { WAIT_VM(0); } else { WAIT_VM(4); }
        BAR();
        bs = bs2;
    }

    const int b_  = m0 >> 9;
    const int h00 = m0 & 511;
    float (*T)[132] = (float(*)[132])lds_s;
#pragma unroll
    for (int q = 0; q < 2; ++q) {
        __syncthreads();
#pragma unroll
        for (int mi = 0; mi < 4; ++mi)
#pragma unroll
        for (int ni = 0; ni < 2; ++ni) {
            int tl = wn * 32 + ni * 16 + lm;
            int hl = wm * 64 + mi * 16 + lk * 4;
            *(float4*)&T[tl][hl] = *(float4*)&acc[q][mi][ni];
        }
        __syncthreads();
        int hg = h00 + q * 128 + (tid & 31) * 4;
        float4 dv = *(const float4*)&Dp[hg];
#pragma unroll
        for (int it = 0; it < 8; ++it) {
            int tl = (tid >> 5) + it * 16;
            int tg = 2 * (n0 + tl) + p;
            size_t gidx = ((size_t)b_ * cL + tg) * cH + hg;
            float4 uv = *(const float4*)&u[gidx];
            float4 yv = *(float4*)&T[tl][(tid & 31) * 4];
            yv.x += dv.x * uv.x;
            yv.y += dv.y * uv.y;
            yv.z += dv.z * uv.z;
            yv.w += dv.w * uv.w;
            *(float4*)&out[gidx] = yv;
        }
    }
}

extern "C" void kernel_launch(void* const* d_in, const int* in_sizes, int n_in,
                              void* d_out, int out_size, void* d_ws, size_t ws_size,
                              hipStream_t stream) {
    const float* u    = (const float*)d_in[0];
    const float* w_re = (const float*)d_in[1];
    const float* w_im = (const float*)d_in[2];
    const float* C_re = (const float*)d_in[3];
    const float* C_im = (const float*)d_in[4];
    const float* Dp   = (const float*)d_in[5];
    const float* dt   = (const float*)d_in[6];
    float* out = (float*)d_out;
    short* Wb  = (short*)d_ws;

    hipLaunchKernelGGL(k_tabs,  dim3(4096), dim3(256), 0, stream, Wb);
    hipLaunchKernelGGL(k_trans, dim3(cL / 64, cH / 64, cB), dim3(256), 0, stream, u, Wb);
    hipLaunchKernelGGL(k_kgen,  dim3(cH), dim3(256), 0, stream,
                       w_re, w_im, C_re, C_im, dt, Wb);
    hipLaunchKernelGGL(k_kfg,   dim3(32, 8), dim3(256), 0, stream, Wb);
    hipLaunchKernelGGL(k_fwd8,  dim3(256), dim3(512), 0, stream, Wb);
    hipLaunchKernelGGL(k_invB,  dim3(256), dim3(512), 0, stream, u, Dp, Wb, out);
}

// Round 19
// 190.275 us; speedup vs baseline: 1.0416x; 1.0035x over previous
//
#include <hip/hip_runtime.h>
#include <hip/hip_bf16.h>
#include <math.h>

// S4DConv via MFMA: B=8, L=2048, H=512, N=64, CH=1
//   r19: coarse-phase GEMM cores — 2 phases/K-tile, 32 MFMA/phase,
//   3 barriers + 1 lgkm + 1 vm per K-tile (was 8/4/2). Reads moved to phase
//   tails (complete under next phase's BAR+lgkm). Hazard audit in comments.

namespace {
constexpr int cB = 8;
constexpr int cL = 2048;
constexpr int cH = 512;
constexpr int cN = 64;
constexpr int M1 = 4095;
constexpr int M2 = 4096;
constexpr int BH = cB * cH;            // 4096
constexpr int MA = BH + cH;            // 4608

constexpr size_t S0   = 2 * ((size_t)cH * cN * 6);
constexpr size_t S_B1 = S0;                           // [4096][2048] paired
constexpr size_t S_A  = S_B1 + (size_t)4096 * 2048;   // [4608][2048]
constexpr size_t S_T2 = S_A  + (size_t)MA * 2048;     // B2 [2][1024][2048]
constexpr size_t S_U  = S_T2 + (size_t)2048 * 4096;   // [4608][4096]: rows<4096 Ae|Ao; 4096+ KF
}

typedef __attribute__((ext_vector_type(8))) short short8;
typedef __attribute__((ext_vector_type(4))) float f32x4;

static __device__ inline short f2bf(float x) {
    __hip_bfloat16 h = __float2bfloat16(x);
    return *reinterpret_cast<short*>(&h);
}
static __device__ inline float bf2f(short s) {
    return __uint_as_float(((unsigned int)(unsigned short)s) << 16);
}
static __device__ __forceinline__ void load_lds16(const short* g, short* l) {
    __builtin_amdgcn_global_load_lds(
        (const __attribute__((address_space(1))) void*)g,
        (__attribute__((address_space(3))) void*)l, 16, 0, 0);
}
#define WAIT_LGKM0() do { asm volatile("s_waitcnt lgkmcnt(0)" ::: "memory"); \
                          __builtin_amdgcn_sched_barrier(0); } while (0)
#define WAIT_VM(n)   do { asm volatile("s_waitcnt vmcnt(" #n ")" ::: "memory"); \
                          __builtin_amdgcn_sched_barrier(0); } while (0)
#define BAR() __builtin_amdgcn_s_barrier()

__global__ __launch_bounds__(256) void k_tabs(short* __restrict__ Wb)
{
    int tid = threadIdx.x;
    if (blockIdx.x < 2048) {              // B1'' rows for DFT j
        int j  = blockIdx.x;
        int base = (j < 1024) ? 4 * j : (j == 1024 ? 2 : 4 * (2048 - j) + 2);
        int t0 = tid * 8;
        int p0 = (int)(((long)j * t0) % M1);
        float c, s, cs, ss;
        sincosf((6.283185307179586f / (float)M1) * (float)p0, &s, &c);
        sincosf((6.283185307179586f / (float)M1) * (float)j,  &ss, &cs);
        short8 vc, vs;
#pragma unroll
        for (int i = 0; i < 8; ++i) {
            vc[i] = f2bf(c); vs[i] = f2bf(s);
            float tr = c * cs - s * ss;
            s = c * ss + s * cs;
            c = tr;
        }
        *(short8*)&Wb[S_B1 + (size_t)base       * 2048 + t0] = vc;
        *(short8*)&Wb[S_B1 + (size_t)(base + 1) * 2048 + t0] = vs;
    } else {                              // B2 parity rows
        int r   = blockIdx.x - 2048;
        int p   = r >> 10, tau = r & 1023;
        int t   = 2 * tau + p;
        int k0  = tid * 8;
        float stepang = (6.283185307179586f / (float)M2) * (float)t;
        float cs, ss; sincosf(stepang, &ss, &cs);
        short8 v;
        if (k0 < 1024) {
            int ph = (k0 * t) & (M2 - 1);
            float c, s; sincosf((6.283185307179586f / (float)M2) * (float)ph, &s, &c);
#pragma unroll
            for (int i = 0; i < 8; ++i) {
                v[i] = f2bf(c);
                float tr = c * cs - s * ss;
                s = c * ss + s * cs;
                c = tr;
            }
        } else {
            int j0 = k0 - 1024;
            int ph = (j0 * t) & (M2 - 1);
            float c, s; sincosf((6.283185307179586f / (float)M2) * (float)ph, &s, &c);
#pragma unroll
            for (int i = 0; i < 8; ++i) {
                int k = k0 + i;
                v[i] = (k == 1024) ? f2bf((tau & 1) ? -1.f : 1.f) : f2bf(s);
                float tr = c * cs - s * ss;
                s = c * ss + s * cs;
                c = tr;
            }
        }
        *(short8*)&Wb[S_T2 + (size_t)r * 2048 + k0] = v;
    }
}

__global__ __launch_bounds__(256) void k_trans(const float* __restrict__ u,
                                               short* __restrict__ Wb)
{
    __shared__ float tile[64][65];
    int t0 = blockIdx.x * 64;
    int h0 = blockIdx.y * 64;
    int b  = blockIdx.z;
    int cx = threadIdx.x & 63, r0 = threadIdx.x >> 6;
#pragma unroll
    for (int i = 0; i < 16; ++i) {
        int row = r0 + i * 4;
        tile[row][cx] = u[((size_t)b * cL + t0 + row) * cH + h0 + cx];
    }
    __syncthreads();
    short* A = Wb + S_A;
#pragma unroll
    for (int i = 0; i < 16; ++i) {
        int hrow = r0 + i * 4;
        A[(size_t)(b * cH + h0 + hrow) * 2048 + t0 + cx] = f2bf(tile[cx][hrow]);
    }
}

__global__ __launch_bounds__(256) void k_kgen(
    const float* __restrict__ w_re, const float* __restrict__ w_im,
    const float* __restrict__ C_re, const float* __restrict__ C_im,
    const float* __restrict__ dt, short* __restrict__ Wb)
{
    __shared__ float md[cN * 6];
    int h = blockIdx.x, tid = threadIdx.x;
    if (tid < cN) {
        int idx = h * cN + tid;
        double dtv = dt[h];
        double wr = w_re[idx], wi = w_im[idx];
        double ar = wr * dtv, ai = wi * dtv;
        double er = exp(ar);
        double zs, zc; sincos(ai, &zs, &zc);
        double zr = er * zc, zi = er * zs;
        double nr = zr - 1.0, ni = zi;
        double inv = 1.0 / (wr * wr + wi * wi);
        double gr = (nr * wr + ni * wi) * inv;
        double gi = (ni * wr - nr * wi) * inv;
        double cr = C_re[idx], ci = C_im[idx];
        md[tid*6+0] = (float)(cr * gr - ci * gi);
        md[tid*6+1] = (float)(cr * gi + ci * gr);
        md[tid*6+2] = (float)zr; md[tid*6+3] = (float)zi;
        md[tid*6+4] = (float)ar; md[tid*6+5] = (float)ai;
    }
    __syncthreads();
    int t0 = tid * 8;
    float acc[8] = {0.f, 0.f, 0.f, 0.f, 0.f, 0.f, 0.f, 0.f};
    for (int n = 0; n < cN; ++n) {
        float csr = md[n*6+0], csi = md[n*6+1];
        float zr  = md[n*6+2], zi  = md[n*6+3];
        float ar  = md[n*6+4], ai  = md[n*6+5];
        float mag = expf(ar * (float)t0);
        double ph = fmod((double)ai * (double)t0, 6.283185307179586);
        float s, c; sincosf((float)ph, &s, &c);
        float pr = mag * c, pi = mag * s;
#pragma unroll
        for (int i = 0; i < 8; ++i) {
            acc[i] += csr * pr - csi * pi;
            float tr = pr * zr - pi * zi;
            pi = pr * zi + pi * zr;
            pr = tr;
        }
    }
    short8 v;
#pragma unroll
    for (int i = 0; i < 8; ++i) v[i] = f2bf(2.f * acc[i]);
    *reinterpret_cast<short8*>(&Wb[S_A + (size_t)(BH + h) * 2048 + t0]) = v;
}

#define MFMA16(AR, BR, ACC) \
    _Pragma("unroll") for (int kk = 0; kk < 2; ++kk) \
    _Pragma("unroll") for (int ni = 0; ni < 2; ++ni) \
    _Pragma("unroll") for (int mi = 0; mi < 4; ++mi) \
        ACC[mi][ni] = __builtin_amdgcn_mfma_f32_16x16x32_bf16(AR[mi][kk], BR[ni][kk], ACC[mi][ni], 0, 0, 0);

// ------- 256x256 coarse 2-phase core: 3 BAR + 1 lgkm + 1 vm per K-tile ------
// P0(t): rd b1(t),a1(t); BAR; lgkm0; MFMA Q00,Q01; BAR.
//   (lgkm0-before-BAR2 guarantees all waves' reads of slot(t&1) complete
//    before any wave's P1 stage overwrites it.)
// P1(t): stage tile t+2 (slot t&1); vm(8) retires tile t+1's batch (issued
//   P1(t-1), 2 phases old); BAR publishes; MFMA Q11,Q10 (regs only);
//   rd a0,b0(t+1) at tail (complete under P0(t+1)'s BAR+lgkm0).
__device__ __forceinline__ void gemm2p_core(
    const short* __restrict__ Ag, int lda,
    const short* __restrict__ Bg, int ldb,
    int m0, int n0, int nt, short* lds, f32x4 (&acc)[4][4][2])
{
    const int tid  = threadIdx.x;
    const int wave = tid >> 6, lane = tid & 63;
    const int wm = wave >> 2, wn = wave & 3;
    const int lm = lane & 15, lk = lane >> 4;
    const int srow8 = lane >> 3;
    const int scol  = (lane & 7) * 8;

    auto stage = [&](const short* G, int ldg, int row0, int half, int kt, int sb) {
        short* l0 = lds + sb + (size_t)((kt & 1) * 2 + half) * 8192;
#pragma unroll
        for (int q = 0; q < 2; ++q) {
            int chunk = wave * 2 + q;
            int r = chunk * 8 + srow8;
            int c = scol ^ ((r & 7) << 3);
            load_lds16(G + (size_t)(row0 + half * 128 + r) * ldg + kt * 64 + c,
                       l0 + chunk * 512);
        }
    };
    auto rdA = [&](int qa, int kt, int mi, int kk) -> short8 {
        int rl = wm * 64 + mi * 16 + lm;
        int c  = (kk * 32 + lk * 8) ^ ((rl & 7) << 3);
        return *(const short8*)(lds + (size_t)((kt & 1) * 2 + qa) * 8192 + rl * 64 + c);
    };
    auto rdB = [&](int qb, int kt, int ni, int kk) -> short8 {
        int rl = wn * 32 + ni * 16 + lm;
        int c  = (kk * 32 + lk * 8) ^ ((rl & 7) << 3);
        return *(const short8*)(lds + 32768 + (size_t)((kt & 1) * 2 + qb) * 8192 + rl * 64 + c);
    };

    // prologue: tiles 0,1 fully staged (16 loads); vm(8) = tile 0 landed
    stage(Ag, lda, m0, 0, 0, 0);
    stage(Bg, ldb, n0, 0, 0, 32768);
    stage(Bg, ldb, n0, 1, 0, 32768);
    stage(Ag, lda, m0, 1, 0, 0);
    stage(Ag, lda, m0, 0, 1, 0);
    stage(Bg, ldb, n0, 0, 1, 32768);
    stage(Bg, ldb, n0, 1, 1, 32768);
    stage(Ag, lda, m0, 1, 1, 0);
    WAIT_VM(8);
    BAR();

    short8 a0[4][2], a1[4][2], b0[2][2], b1[2][2];
#pragma unroll
    for (int mi = 0; mi < 4; ++mi) { a0[mi][0] = rdA(0, 0, mi, 0); a0[mi][1] = rdA(0, 0, mi, 1); }
#pragma unroll
    for (int ni = 0; ni < 2; ++ni) { b0[ni][0] = rdB(0, 0, ni, 0); b0[ni][1] = rdB(0, 0, ni, 1); }

    for (int t = 0; t < nt; ++t) {
        const bool st = (t + 2 < nt);
        const bool rd = (t + 1 < nt);
        // ---- P0 ----
#pragma unroll
        for (int ni = 0; ni < 2; ++ni) { b1[ni][0] = rdB(1, t, ni, 0); b1[ni][1] = rdB(1, t, ni, 1); }
#pragma unroll
        for (int mi = 0; mi < 4; ++mi) { a1[mi][0] = rdA(1, t, mi, 0); a1[mi][1] = rdA(1, t, mi, 1); }
        BAR();
        WAIT_LGKM0();
        __builtin_amdgcn_s_setprio(1);
        MFMA16(a0, b0, acc[0]);
        MFMA16(a0, b1, acc[1]);
        __builtin_amdgcn_s_setprio(0);
        BAR();
        // ---- P1 ----
        if (st) {
            stage(Ag, lda, m0, 0, t + 2, 0);
            stage(Bg, ldb, n0, 0, t + 2, 32768);
            stage(Bg, ldb, n0, 1, t + 2, 32768);
            stage(Ag, lda, m0, 1, t + 2, 0);
            WAIT_VM(8);
        } else {
            WAIT_VM(0);
        }
        BAR();
        __builtin_amdgcn_s_setprio(1);
        MFMA16(a1, b1, acc[3]);
        MFMA16(a1, b0, acc[2]);
        __builtin_amdgcn_s_setprio(0);
        if (rd) {
#pragma unroll
            for (int mi = 0; mi < 4; ++mi) { a0[mi][0] = rdA(0, t + 1, mi, 0); a0[mi][1] = rdA(0, t + 1, mi, 1); }
#pragma unroll
            for (int ni = 0; ni < 2; ++ni) { b0[ni][0] = rdB(0, t + 1, ni, 0); b0[ni][1] = rdB(0, t + 1, ni, 1); }
        }
    }
}

// forward: acc = A_u x B1''^T; epilogue: mix (x KF) + parity fold -> Ae|Ao
__global__ __launch_bounds__(512, 2) void k_fwd8(short* __restrict__ Wb)
{
    __shared__ short lds_s[65536];
    int xcd = blockIdx.x & 7, idx = blockIdx.x >> 3;
    const int m0 = (((xcd >> 1) << 2) + (idx >> 3)) * 256;
    const int n0 = (((xcd & 1) << 3) + (idx & 7)) * 256;
    const int tid = threadIdx.x;
    const int wave = tid >> 6, lane = tid & 63;
    const int wm = wave >> 2, wn = wave & 3;
    const int lm = lane & 15, lk = lane >> 4;

    f32x4 acc[4][4][2] = {};
    gemm2p_core(Wb + S_A, 2048, Wb + S_B1, 2048, m0, n0, 32, lds_s, acc);

    short* Uw = Wb + S_U;
    const short* KF = Wb + S_U;
    short (*M)[136] = (short(*)[136])lds_s;
    for (int q = 0; q < 4; ++q) {
        __syncthreads();
#pragma unroll
        for (int mi = 0; mi < 4; ++mi)
#pragma unroll
        for (int ni = 0; ni < 2; ++ni)
#pragma unroll
        for (int r = 0; r < 4; ++r)
            M[wm * 64 + mi * 16 + lk * 4 + r][wn * 32 + ni * 16 + lm] =
                f2bf(acc[q][mi][ni][r]);
        __syncthreads();
        const int pq0 = (n0 >> 2) + (q & 1) * 32;
        int rl = tid >> 2;
        int cp = (tid & 3) * 8;
        int rowg = m0 + (q >> 1) * 128 + rl;
        int h = rowg & (cH - 1);
        int colg = n0 + (q & 1) * 128 + cp * 4;
        short8 kf4[4], m4[4];
#pragma unroll
        for (int w = 0; w < 4; ++w) {
            kf4[w] = *(const short8*)&KF[(size_t)(4096 + h) * 4096 + colg + w * 8];
            m4[w]  = *(const short8*)&M[rl][cp * 4 + w * 8];
        }
        short8 vce, vse, vco, vso;
#pragma unroll
        for (int i = 0; i < 8; ++i) {
            int w = i >> 1, o = (i & 1) * 4;
            float C  = bf2f(m4[w][o]),   S  = bf2f(m4[w][o+1]);
            float C2 = bf2f(m4[w][o+2]), S2 = bf2f(m4[w][o+3]);
            float Ck  = bf2f(kf4[w][o]),   Sk  = bf2f(kf4[w][o+1]);
            float Ck2 = bf2f(kf4[w][o+2]), Sk2 = bf2f(kf4[w][o+3]);
            int pp = pq0 + cp + i;
            float scp = (pp == 0 ? 1.0f : 2.0f) * (1.0f / (float)M2);
            float scq = 2.0f / (float)M2;
            float yrp = scp * (Ck * C - Sk * S);
            float yip = scp * (Ck * S + Sk * C);
            float yrq = scq * (Ck2 * C2 - Sk2 * S2);
            float yiq = scq * (Ck2 * S2 + Sk2 * C2);
            float ce, co, se, so;
            if (pp == 0) { ce = yrp; co = yrp; se = yrq; so = yiq; }
            else { ce = yrp + yrq; co = yrp - yrq; se = yip - yiq; so = yip + yiq; }
            vce[i] = f2bf(ce); vco[i] = f2bf(co);
            vse[i] = f2bf(se); vso[i] = f2bf(so);
        }
        size_t base = (size_t)rowg * 4096;
        int kx = pq0 + cp;
        *(short8*)&Uw[base + kx]        = vce;
        *(short8*)&Uw[base + 1024 + kx] = vse;
        *(short8*)&Uw[base + 2048 + kx] = vco;
        *(short8*)&Uw[base + 3072 + kx] = vso;
    }
}

// KF rows: U[4096+h] = A_k x B1''^T ; 64x128 tiles, grid (32,8) = 256 blocks
__global__ __launch_bounds__(256, 2) void k_kfg(short* __restrict__ Wb)
{
    __shared__ __align__(16) short As[64][32];
    __shared__ __align__(16) short Bs[128][32];
    const short* A = Wb + S_A;
    const short* B = Wb + S_B1;
    short* U = Wb + S_U;
    const int tid = threadIdx.x;
    const int m0 = 4096 + blockIdx.y * 64, n0 = blockIdx.x * 128;
    const int wave = tid >> 6, lane = tid & 63;
    const int wr = wave >> 1, wc = wave & 1;
    const int lm = lane & 15, lk = lane >> 4;
    const int srowA = tid >> 2,  scolA = (tid & 3) * 8;
    const int srowB = lane >> 2, scolB = (lane & 3) * 8;

    f32x4 acc[2][4] = {};
    for (int k0 = 0; k0 < 2048; k0 += 32) {
        __syncthreads();
        load_lds16(&A[(size_t)(m0 + srowA) * 2048 + k0 + scolA],
                   &As[0][0] + wave * 512);
#pragma unroll
        for (int q = 0; q < 2; ++q) {
            int chunk = wave * 2 + q;
            load_lds16(&B[(size_t)(n0 + chunk * 16 + srowB) * 2048 + k0 + scolB],
                       &Bs[chunk * 16][0]);
        }
        __syncthreads();
        short8 a[2];
#pragma unroll
        for (int mi = 0; mi < 2; ++mi)
            a[mi] = *(const short8*)&As[wr*32 + mi*16 + lm][lk*8];
#pragma unroll
        for (int ni = 0; ni < 4; ++ni) {
            short8 b = *(const short8*)&Bs[wc*64 + ni*16 + lm][lk*8];
#pragma unroll
            for (int mi = 0; mi < 2; ++mi)
                acc[mi][ni] = __builtin_amdgcn_mfma_f32_16x16x32_bf16(a[mi], b, acc[mi][ni], 0, 0, 0);
        }
    }
#pragma unroll
    for (int mi = 0; mi < 2; ++mi)
#pragma unroll
    for (int ni = 0; ni < 4; ++ni)
#pragma unroll
    for (int r = 0; r < 4; ++r) {
        int row = m0 + wr*32 + mi*16 + lk*4 + r;
        int col = n0 + wc*64 + ni*16 + lm;
        U[(size_t)row * 4096 + col] = f2bf(acc[mi][ni][r]);
    }
}

// inverse: per parity p, y[2tau+p] = A(e/o) x B2_p^T, K=2048, BM=256 x BN=128
// coarse 2-phase: P0{rd a1; BAR; lgkm0; MFMA(a0,b); BAR}
//                 P1{stage A1(t+2),A0(t+2),B(t+3); vm(6); BAR; MFMA(a1,b);
//                    rd a0,b(t+1) at tail}
__global__ __launch_bounds__(512, 1) void k_invB(const float* __restrict__ u,
                                                 const float* __restrict__ Dp,
                                                 short* __restrict__ Wb,
                                                 float* __restrict__ out)
{
    __shared__ short lds_s[57344];   // 112 KB
    int xcd = blockIdx.x & 7, idx = blockIdx.x >> 3;
    const int m0 = ((((xcd >> 1) << 2) + (idx >> 3))) * 256;   // bh
    const int nj = ((xcd & 1) << 3) + (idx & 7);               // 0..15
    const int p  = nj >> 3;
    const int n0 = (nj & 7) * 128;                             // tau0
    const int tid = threadIdx.x;
    const int wave = tid >> 6, lane = tid & 63;
    const int wm = wave >> 2, wn = wave & 3;
    const int lm = lane & 15, lk = lane >> 4;
    const int srow8 = lane >> 3;
    const int scol  = (lane & 7) * 8;
    constexpr int nt = 32;
    short* lds = lds_s;
    const short* Ag = Wb + S_U + (size_t)p * 2048;
    const short* Bg = Wb + S_T2 + (size_t)p * 1024 * 2048;

    auto stageA = [&](int half, int kt) {
        short* l0 = lds + (size_t)((kt & 1) * 2 + half) * 8192;
#pragma unroll
        for (int q = 0; q < 2; ++q) {
            int chunk = wave * 2 + q;
            int r = chunk * 8 + srow8;
            int c = scol ^ ((r & 7) << 3);
            load_lds16(Ag + (size_t)(m0 + half * 128 + r) * 4096 + kt * 64 + c,
                       l0 + chunk * 512);
        }
    };
    auto stageB = [&](int kt, int slot) {
        short* l0 = lds + 32768 + (size_t)slot * 8192;
#pragma unroll
        for (int q = 0; q < 2; ++q) {
            int chunk = wave * 2 + q;
            int r = chunk * 8 + srow8;
            int c = scol ^ ((r & 7) << 3);
            load_lds16(Bg + (size_t)(n0 + r) * 2048 + kt * 64 + c,
                       l0 + chunk * 512);
        }
    };
    auto rdA = [&](int half, int kt, int mi, int kk) -> short8 {
        int rl = wm * 64 + mi * 16 + lm;
        int c  = (kk * 32 + lk * 8) ^ ((rl & 7) << 3);
        return *(const short8*)(lds + (size_t)((kt & 1) * 2 + half) * 8192 + rl * 64 + c);
    };
    auto rdB = [&](int slot, int ni, int kk) -> short8 {
        int rl = wn * 32 + ni * 16 + lm;
        int c  = (kk * 32 + lk * 8) ^ ((rl & 7) << 3);
        return *(const short8*)(lds + 32768 + (size_t)slot * 8192 + rl * 64 + c);
    };

    f32x4 acc[2][4][2] = {};

    // prologue: A0(0),B(0),A1(0),A0(1),A1(1),B(1),B(2)  [14 loads]
    stageA(0, 0);
    stageB(0, 0);
    stageA(1, 0);
    stageA(0, 1);
    stageA(1, 1);
    stageB(1, 1);
    stageB(2, 2);
    WAIT_VM(8);                  // A0(0),B(0),A1(0) landed
    BAR();
    short8 a0[4][2], a1[4][2], b[2][2];
#pragma unroll
    for (int mi = 0; mi < 4; ++mi) { a0[mi][0] = rdA(0, 0, mi, 0); a0[mi][1] = rdA(0, 0, mi, 1); }
#pragma unroll
    for (int ni = 0; ni < 2; ++ni) { b[ni][0] = rdB(0, ni, 0); b[ni][1] = rdB(0, ni, 1); }

    int bs = 0;
    for (int t = 0; t < nt; ++t) {
        const bool r1 = (t + 1 < nt);
        const bool s2 = (t + 2 < nt);
        const bool s3 = (t + 3 < nt);
        const bool tail = (t >= nt - 3);
        const int bs2 = (bs == 2) ? 0 : bs + 1;
        // ---- P0 ----
#pragma unroll
        for (int mi = 0; mi < 4; ++mi) { a1[mi][0] = rdA(1, t, mi, 0); a1[mi][1] = rdA(1, t, mi, 1); }
        BAR();
        WAIT_LGKM0();
        __builtin_amdgcn_s_setprio(1);
        MFMA16(a0, b, acc[0]);
        __builtin_amdgcn_s_setprio(0);
        BAR();
        // ---- P1 ----
        if (s2) { stageA(1, t + 2); stageA(0, t + 2); }
        if (s3) stageB(t + 3, bs);
        if (tail) { WAIT_VM(0); } else { WAIT_VM(6); }
        BAR();
        __builtin_amdgcn_s_setprio(1);
        MFMA16(a1, b, acc[1]);
        __builtin_amdgcn_s_setprio(0);
        if (r1) {
#pragma unroll
            for (int mi = 0; mi < 4; ++mi) { a0[mi][0] = rdA(0, t + 1, mi, 0); a0[mi][1] = rdA(0, t + 1, mi, 1); }
#pragma unroll
            for (int ni = 0; ni < 2; ++ni) { b[ni][0] = rdB(bs2, ni, 0); b[ni][1] = rdB(bs2, ni, 1); }
        }
        bs = bs2;
    }

    const int b_  = m0 >> 9;
    const int h00 = m0 & 511;
    float (*T)[132] = (float(*)[132])lds_s;
#pragma unroll
    for (int q = 0; q < 2; ++q) {
        __syncthreads();
#pragma unroll
        for (int mi = 0; mi < 4; ++mi)
#pragma unroll
        for (int ni = 0; ni < 2; ++ni) {
            int tl = wn * 32 + ni * 16 + lm;
            int hl = wm * 64 + mi * 16 + lk * 4;
            *(float4*)&T[tl][hl] = *(float4*)&acc[q][mi][ni];
        }
        __syncthreads();
        int hg = h00 + q * 128 + (tid & 31) * 4;
        float4 dv = *(const float4*)&Dp[hg];
#pragma unroll
        for (int it = 0; it < 8; ++it) {
            int tl = (tid >> 5) + it * 16;
            int tg = 2 * (n0 + tl) + p;
            size_t gidx = ((size_t)b_ * cL + tg) * cH + hg;
            float4 uv = *(const float4*)&u[gidx];
            float4 yv = *(float4*)&T[tl][(tid & 31) * 4];
            yv.x += dv.x * uv.x;
            yv.y += dv.y * uv.y;
            yv.z += dv.z * uv.z;
            yv.w += dv.w * uv.w;
            *(float4*)&out[gidx] = yv;
        }
    }
}

extern "C" void kernel_launch(void* const* d_in, const int* in_sizes, int n_in,
                              void* d_out, int out_size, void* d_ws, size_t ws_size,
                              hipStream_t stream) {
    const float* u    = (const float*)d_in[0];
    const float* w_re = (const float*)d_in[1];
    const float* w_im = (const float*)d_in[2];
    const float* C_re = (const float*)d_in[3];
    const float* C_im = (const float*)d_in[4];
    const float* Dp   = (const float*)d_in[5];
    const float* dt   = (const float*)d_in[6];
    float* out = (float*)d_out;
    short* Wb  = (short*)d_ws;

    hipLaunchKernelGGL(k_tabs,  dim3(4096), dim3(256), 0, stream, Wb);
    hipLaunchKernelGGL(k_trans, dim3(cL / 64, cH / 64, cB), dim3(256), 0, stream, u, Wb);
    hipLaunchKernelGGL(k_kgen,  dim3(cH), dim3(256), 0, stream,
                       w_re, w_im, C_re, C_im, dt, Wb);
    hipLaunchKernelGGL(k_kfg,   dim3(32, 8), dim3(256), 0, stream, Wb);
    hipLaunchKernelGGL(k_fwd8,  dim3(256), dim3(512), 0, stream, Wb);
    hipLaunchKernelGGL(k_invB,  dim3(256), dim3(512), 0, stream, u, Dp, Wb, out);
}